// Round 1
// baseline (1260.406 us; speedup 1.0000x reference)
//
#include <hip/hip_runtime.h>
#include <math.h>

// ---------------- CSR build ----------------
__global__ void hist_kernel(const int* __restrict__ src, const int* __restrict__ dst,
                            int* __restrict__ cnt_in, int* __restrict__ cnt_out, int E) {
  int e = blockIdx.x * blockDim.x + threadIdx.x;
  if (e < E) {
    atomicAdd(&cnt_out[src[e]], 1);
    atomicAdd(&cnt_in[dst[e]], 1);
  }
}

__global__ void invsqrt_kernel(const int* __restrict__ cin, const int* __restrict__ cout,
                               float* __restrict__ din_is, float* __restrict__ dout_is, int N) {
  int i = blockIdx.x * blockDim.x + threadIdx.x;
  if (i < N) {
    int a = cin[i];  if (a < 1) a = 1;
    int b = cout[i]; if (b < 1) b = 1;
    din_is[i]  = rsqrtf((float)a);
    dout_is[i] = rsqrtf((float)b);
  }
}

// exclusive scan, 1024 elements per block
__global__ void scan1_kernel(const int* __restrict__ cnt, int* __restrict__ out,
                             int* __restrict__ bsum, int N) {
  __shared__ int sh[256];
  int t = threadIdx.x;
  int base = blockIdx.x * 1024 + t * 4;
  int v0=0,v1=0,v2=0,v3=0;
  if (base+0 < N) v0 = cnt[base+0];
  if (base+1 < N) v1 = cnt[base+1];
  if (base+2 < N) v2 = cnt[base+2];
  if (base+3 < N) v3 = cnt[base+3];
  int s = v0+v1+v2+v3;
  sh[t] = s;
  __syncthreads();
  for (int off=1; off<256; off<<=1){
    int x = (t >= off) ? sh[t-off] : 0;
    __syncthreads();
    sh[t] += x;
    __syncthreads();
  }
  if (t == 255) bsum[blockIdx.x] = sh[255];
  int run = sh[t] - s;
  if (base+0 < N) out[base+0] = run; run += v0;
  if (base+1 < N) out[base+1] = run; run += v1;
  if (base+2 < N) out[base+2] = run; run += v2;
  if (base+3 < N) out[base+3] = run;
}

__global__ void scan2_kernel(const int* __restrict__ bsum, int* __restrict__ boff, int nb) {
  __shared__ int sh[256];
  int t = threadIdx.x;
  int v = (t < nb) ? bsum[t] : 0;
  sh[t] = v;
  __syncthreads();
  for (int off=1; off<256; off<<=1){
    int x = (t >= off) ? sh[t-off] : 0;
    __syncthreads();
    sh[t] += x;
    __syncthreads();
  }
  if (t < nb) boff[t] = sh[t] - v;
}

__global__ void scan3_kernel(int* __restrict__ rp, int* __restrict__ cursor,
                             const int* __restrict__ boff, int N, int E) {
  int i = blockIdx.x * blockDim.x + threadIdx.x;
  if (i < N) { int v = rp[i] + boff[i >> 10]; rp[i] = v; cursor[i] = v; }
  if (i == 0) rp[N] = E;
}

__global__ void scatter_kernel(const int* __restrict__ src, const int* __restrict__ dst,
                               int* __restrict__ cursor, int* __restrict__ col, int E) {
  int e = blockIdx.x * blockDim.x + threadIdx.x;
  if (e < E) {
    int p = atomicAdd(&cursor[dst[e]], 1);
    col[p] = src[e];
  }
}

// ---------------- aggregation: out[d] = din[d] * sum_{s in in(d)} dout[s]*h[s], D=128 ----------------
__global__ __launch_bounds__(256) void agg128_kernel(
    const float* __restrict__ h, const int* __restrict__ rp, const int* __restrict__ col,
    const float* __restrict__ dout_is, const float* __restrict__ din_is,
    float* __restrict__ out, int N) {
  int wid  = (blockIdx.x * blockDim.x + threadIdx.x) >> 6;  // one wave per dst node
  int lane = threadIdx.x & 63;
  if (wid >= N) return;
  int s0 = rp[wid], s1 = rp[wid+1];
  float ax = 0.f, ay = 0.f;
  const float2* __restrict__ h2 = (const float2*)h;
  for (int e = s0; e < s1; ++e) {
    int s = col[e];                 // wave-uniform -> scalar load
    float w = dout_is[s];           // wave-uniform
    float2 v = h2[(size_t)s*64 + lane];
    ax += w * v.x; ay += w * v.y;
  }
  float di = din_is[wid];
  float2 r; r.x = ax*di; r.y = ay*di;
  ((float2*)out)[(size_t)wid*64 + lane] = r;
}

// ---------------- GEMM: Out[N,F] = A[N,128] @ W[128,F] (+bias), in-place safe ----------------
template<int F, int TX, int CPT, int RPT>
__global__ __launch_bounds__(256) void gemm_kernel(
    const float* __restrict__ A, const float* __restrict__ W, const float* __restrict__ bias,
    float* __restrict__ Out, int N, int ntiles) {
  static_assert(TX*CPT == F, "cols");
  static_assert((256/TX)*RPT == 64, "rows");
  __shared__ float As[64][132];       // 64 rows x 128 K (+pad)
  __shared__ float Ws[32*F];          // K-chunk of W
  int tid = threadIdx.x;
  int tx = tid % TX;
  int ty = tid / TX;
  for (int tile = blockIdx.x; tile < ntiles; tile += gridDim.x) {
    int row0 = tile * 64;
    float acc[RPT][CPT];
    #pragma unroll
    for (int r=0;r<RPT;r++)
      #pragma unroll
      for (int j=0;j<CPT;j++) acc[r][j] = 0.f;
    __syncthreads();   // protect As from previous tile's readers
    #pragma unroll
    for (int i=0;i<8;i++){
      int idx = tid + i*256;          // 2048 float4 slots
      int r = idx >> 5;
      int c = (idx & 31) << 2;
      float4 v = make_float4(0.f,0.f,0.f,0.f);
      int gr = row0 + r;
      if (gr < N) v = *(const float4*)(A + (size_t)gr*128 + c);
      *(float4*)(&As[r][c]) = v;
    }
    for (int kc=0; kc<128; kc+=32) {
      __syncthreads();  // prev chunk compute done (and As staged at kc=0 after next sync)
      for (int i = tid; i < 32*F/4; i += 256)
        ((float4*)Ws)[i] = ((const float4*)(W + (size_t)kc*F))[i];
      __syncthreads();
      #pragma unroll 4
      for (int k=0;k<32;k++){
        float a[RPT];
        #pragma unroll
        for (int r=0;r<RPT;r++) a[r] = As[ty*RPT + r][kc + k];
        float b[CPT];
        #pragma unroll
        for (int j=0;j<CPT;j++) b[j] = Ws[k*F + tx*CPT + j];
        #pragma unroll
        for (int r=0;r<RPT;r++)
          #pragma unroll
          for (int j=0;j<CPT;j++)
            acc[r][j] += a[r]*b[j];
      }
    }
    #pragma unroll
    for (int r=0;r<RPT;r++){
      int gr = row0 + ty*RPT + r;
      if (gr < N){
        #pragma unroll
        for (int j=0;j<CPT;j++){
          int c = tx*CPT + j;
          float v = acc[r][j];
          if (bias) v += bias[c];
          Out[(size_t)gr*F + c] = v;
        }
      }
    }
  }
}

// ---------------- BatchNorm ----------------
__global__ void bn_reduce_kernel(const float* __restrict__ h, float* __restrict__ gsum,
                                 float* __restrict__ gsumsq, int N, int rpb) {
  int f = threadIdx.x;                 // 128 threads = 128 cols
  int r0 = blockIdx.x * rpb;
  int r1 = r0 + rpb; if (r1 > N) r1 = N;
  float s = 0.f, ss = 0.f;
  for (int r = r0; r < r1; ++r) {
    float v = h[(size_t)r*128 + f];
    s += v; ss += v*v;
  }
  atomicAdd(&gsum[f], s);
  atomicAdd(&gsumsq[f], ss);
}

__global__ void bn_params_kernel(const float* __restrict__ gsum, const float* __restrict__ gsumsq,
                                 const float* __restrict__ g, const float* __restrict__ be,
                                 float* __restrict__ colA, float* __restrict__ colB, float invN) {
  int f = threadIdx.x;
  float mu  = gsum[f] * invN;
  float var = gsumsq[f] * invN - mu*mu;
  if (var < 0.f) var = 0.f;
  float rs = rsqrtf(var + 1e-5f);
  float a = g[f] * rs;
  colA[f] = a;
  colB[f] = be[f] - mu*a;
}

__global__ void bn_apply_kernel(const float* __restrict__ raw, const float* __restrict__ colA,
                                const float* __restrict__ colB, float* __restrict__ out, int n4) {
  int i = blockIdx.x * blockDim.x + threadIdx.x;
  if (i >= n4) return;
  float4 v = ((const float4*)raw)[i];
  int c4 = i & 31;                     // D=128 -> 32 float4 per row
  float4 a = ((const float4*)colA)[c4];
  float4 b = ((const float4*)colB)[c4];
  v.x = fmaxf(v.x*a.x + b.x, 0.f);
  v.y = fmaxf(v.y*a.y + b.y, 0.f);
  v.z = fmaxf(v.z*a.z + b.z, 0.f);
  v.w = fmaxf(v.w*a.w + b.w, 0.f);
  ((float4*)out)[i] = v;
}

// ---------------- layer 3: aggregate 40-dim + bias + log_softmax ----------------
__global__ __launch_bounds__(256) void final_kernel(
    const float* __restrict__ t, const int* __restrict__ rp, const int* __restrict__ col,
    const float* __restrict__ dout_is, const float* __restrict__ din_is,
    const float* __restrict__ b3, float* __restrict__ out, int N, int C) {
  int wid  = (blockIdx.x * blockDim.x + threadIdx.x) >> 6;
  int lane = threadIdx.x & 63;
  if (wid >= N) return;
  int lf = lane < C ? lane : C-1;
  int s0 = rp[wid], s1 = rp[wid+1];
  float acc = 0.f;
  for (int e = s0; e < s1; ++e) {
    int s = col[e];
    float w = dout_is[s];
    acc += w * t[(size_t)s*C + lf];
  }
  float z = (lane < C) ? din_is[wid]*acc + b3[lf] : -1e30f;
  float m = z;
  #pragma unroll
  for (int off=32; off>0; off>>=1) m = fmaxf(m, __shfl_xor(m, off));
  float ex = expf(z - m);
  float sum = ex;
  #pragma unroll
  for (int off=32; off>0; off>>=1) sum += __shfl_xor(sum, off);
  if (lane < C) out[(size_t)wid*C + lane] = z - m - logf(sum);
}

// ---------------- host ----------------
extern "C" void kernel_launch(void* const* d_in, const int* in_sizes, int n_in,
                              void* d_out, int out_size, void* d_ws, size_t ws_size,
                              hipStream_t stream) {
  const float* x   = (const float*)d_in[0];
  const int*   src = (const int*)d_in[1];
  const int*   dst = (const int*)d_in[2];
  const float* W1  = (const float*)d_in[3];
  const float* b1  = (const float*)d_in[4];
  const float* g1  = (const float*)d_in[5];
  const float* be1 = (const float*)d_in[6];
  const float* W2  = (const float*)d_in[7];
  const float* b2  = (const float*)d_in[8];
  const float* g2  = (const float*)d_in[9];
  const float* be2 = (const float*)d_in[10];
  const float* W3  = (const float*)d_in[11];
  const float* b3  = (const float*)d_in[12];
  const int E = in_sizes[1];
  const int D = in_sizes[4];     // 128
  const int C = in_sizes[12];    // 40
  const int N = in_sizes[0] / D; // 100000
  float* out = (float*)d_out;

  char* p = (char*)d_ws;
  auto alloc = [&](size_t bytes) { char* q = p; p += (bytes + 255) & ~(size_t)255; return q; };
  int* rp        = (int*)alloc((size_t)(N+1)*4);
  int* cursor    = (int*)alloc((size_t)N*4);
  int* cnt_in    = (int*)alloc((size_t)N*4);
  int* cnt_out   = (int*)alloc((size_t)N*4);
  int* bsum      = (int*)alloc(256*4);
  int* boff      = (int*)alloc(256*4);
  float* din_is  = (float*)alloc((size_t)N*4);
  float* dout_is = (float*)alloc((size_t)N*4);
  float* gsum    = (float*)alloc((size_t)D*4);
  float* gsumsq  = (float*)alloc((size_t)D*4);
  float* colA    = (float*)alloc((size_t)D*4);
  float* colB    = (float*)alloc((size_t)D*4);
  int*   col     = (int*)alloc((size_t)E*4);
  float* bufA    = (float*)alloc((size_t)N*D*4);
  float* bufB    = (float*)alloc((size_t)N*D*4);

  hipMemsetAsync(cnt_in, 0, (size_t)N*4, stream);
  hipMemsetAsync(cnt_out, 0, (size_t)N*4, stream);
  int eb  = (E + 255)/256;
  int nbN = (N + 255)/256;
  hist_kernel<<<eb, 256, 0, stream>>>(src, dst, cnt_in, cnt_out, E);
  invsqrt_kernel<<<nbN, 256, 0, stream>>>(cnt_in, cnt_out, din_is, dout_is, N);
  int nb = (N + 1023)/1024;
  scan1_kernel<<<nb, 256, 0, stream>>>(cnt_in, rp, bsum, N);
  scan2_kernel<<<1, 256, 0, stream>>>(bsum, boff, nb);
  scan3_kernel<<<nbN, 256, 0, stream>>>(rp, cursor, boff, N, E);
  scatter_kernel<<<eb, 256, 0, stream>>>(src, dst, cursor, col, E);

  int aggb   = (N + 3)/4;          // 4 waves (nodes) per block
  int ntiles = (N + 63)/64;
  const int gemmGrid = 512;
  int rpb  = (N + 511)/512;
  int nel4 = (N*D)/4;

  // layer 1
  agg128_kernel<<<aggb, 256, 0, stream>>>(x, rp, col, dout_is, din_is, bufA, N);
  gemm_kernel<128,16,8,4><<<gemmGrid, 256, 0, stream>>>(bufA, W1, b1, bufA, N, ntiles);
  hipMemsetAsync(gsum, 0, (size_t)D*4, stream);
  hipMemsetAsync(gsumsq, 0, (size_t)D*4, stream);
  bn_reduce_kernel<<<512, 128, 0, stream>>>(bufA, gsum, gsumsq, N, rpb);
  bn_params_kernel<<<1, 128, 0, stream>>>(gsum, gsumsq, g1, be1, colA, colB, 1.0f/(float)N);
  bn_apply_kernel<<<(nel4+255)/256, 256, 0, stream>>>(bufA, colA, colB, bufB, nel4);

  // layer 2
  agg128_kernel<<<aggb, 256, 0, stream>>>(bufB, rp, col, dout_is, din_is, bufA, N);
  gemm_kernel<128,16,8,4><<<gemmGrid, 256, 0, stream>>>(bufA, W2, b2, bufA, N, ntiles);
  hipMemsetAsync(gsum, 0, (size_t)D*4, stream);
  hipMemsetAsync(gsumsq, 0, (size_t)D*4, stream);
  bn_reduce_kernel<<<512, 128, 0, stream>>>(bufA, gsum, gsumsq, N, rpb);
  bn_params_kernel<<<1, 128, 0, stream>>>(gsum, gsumsq, g2, be2, colA, colB, 1.0f/(float)N);
  bn_apply_kernel<<<(nel4+255)/256, 256, 0, stream>>>(bufA, colA, colB, bufB, nel4);

  // layer 3 (reordered: GEMM to 40 dims first, then aggregate + softmax)
  gemm_kernel<40,8,5,2><<<gemmGrid, 256, 0, stream>>>(bufB, W3, nullptr, bufA, N, ntiles);
  final_kernel<<<aggb, 256, 0, stream>>>(bufA, rp, col, dout_is, din_is, b3, out, N, C);
}

// Round 2
// 999.899 us; speedup vs baseline: 1.2605x; 1.2605x over previous
//
#include <hip/hip_runtime.h>
#include <math.h>

// ---------- bf16 helpers ----------
__device__ inline unsigned short f2bf(float f) {
  union { float f; unsigned u; } v; v.f = f;
  unsigned r = v.u + 0x7fffu + ((v.u >> 16) & 1u);   // round-to-nearest-even
  return (unsigned short)(r >> 16);
}
__device__ inline float bf2f(unsigned short u) {
  union { unsigned u; float f; } v; v.u = ((unsigned)u) << 16;
  return v.f;
}
__device__ inline float2 bfp2f2(unsigned u) {       // packed bf16x2 -> float2
  union { unsigned u; float f; } a, b;
  a.u = u << 16;
  b.u = u & 0xffff0000u;
  float2 r; r.x = a.f; r.y = b.f; return r;
}

// ---------------- CSR build ----------------
__global__ void hist_kernel(const int* __restrict__ src, const int* __restrict__ dst,
                            int* __restrict__ cnt_in, int* __restrict__ cnt_out, int E) {
  int e = blockIdx.x * blockDim.x + threadIdx.x;
  if (e < E) {
    atomicAdd(&cnt_out[src[e]], 1);
    atomicAdd(&cnt_in[dst[e]], 1);
  }
}

__global__ void invsqrt_kernel(const int* __restrict__ cin, const int* __restrict__ cout,
                               float* __restrict__ din_is, float* __restrict__ dout_is, int N) {
  int i = blockIdx.x * blockDim.x + threadIdx.x;
  if (i < N) {
    int a = cin[i];  if (a < 1) a = 1;
    int b = cout[i]; if (b < 1) b = 1;
    din_is[i]  = rsqrtf((float)a);
    dout_is[i] = rsqrtf((float)b);
  }
}

// exclusive scan, 1024 elements per block
__global__ void scan1_kernel(const int* __restrict__ cnt, int* __restrict__ out,
                             int* __restrict__ bsum, int N) {
  __shared__ int sh[256];
  int t = threadIdx.x;
  int base = blockIdx.x * 1024 + t * 4;
  int v0=0,v1=0,v2=0,v3=0;
  if (base+0 < N) v0 = cnt[base+0];
  if (base+1 < N) v1 = cnt[base+1];
  if (base+2 < N) v2 = cnt[base+2];
  if (base+3 < N) v3 = cnt[base+3];
  int s = v0+v1+v2+v3;
  sh[t] = s;
  __syncthreads();
  for (int off=1; off<256; off<<=1){
    int x = (t >= off) ? sh[t-off] : 0;
    __syncthreads();
    sh[t] += x;
    __syncthreads();
  }
  if (t == 255) bsum[blockIdx.x] = sh[255];
  int run = sh[t] - s;
  if (base+0 < N) out[base+0] = run; run += v0;
  if (base+1 < N) out[base+1] = run; run += v1;
  if (base+2 < N) out[base+2] = run; run += v2;
  if (base+3 < N) out[base+3] = run;
}

__global__ void scan2_kernel(const int* __restrict__ bsum, int* __restrict__ boff, int nb) {
  __shared__ int sh[256];
  int t = threadIdx.x;
  int v = (t < nb) ? bsum[t] : 0;
  sh[t] = v;
  __syncthreads();
  for (int off=1; off<256; off<<=1){
    int x = (t >= off) ? sh[t-off] : 0;
    __syncthreads();
    sh[t] += x;
    __syncthreads();
  }
  if (t < nb) boff[t] = sh[t] - v;
}

__global__ void scan3_kernel(int* __restrict__ rp, int* __restrict__ cursor,
                             const int* __restrict__ boff, int N, int E) {
  int i = blockIdx.x * blockDim.x + threadIdx.x;
  if (i < N) { int v = rp[i] + boff[i >> 10]; rp[i] = v; cursor[i] = v; }
  if (i == 0) rp[N] = E;
}

__global__ void scatter_kernel(const int* __restrict__ src, const int* __restrict__ dst,
                               int* __restrict__ cursor, int* __restrict__ col, int E) {
  int e = blockIdx.x * blockDim.x + threadIdx.x;
  if (e < E) {
    int p = atomicAdd(&cursor[dst[e]], 1);
    col[p] = src[e];
  }
}

// ---------------- cast x (fp32 row) -> bf16 row pre-scaled by dout_is ----------------
__global__ void cast_scale_kernel(const float* __restrict__ x, const float* __restrict__ dout_is,
                                  unsigned* __restrict__ xb2, int n4) {
  int i = blockIdx.x * blockDim.x + threadIdx.x;   // one float4 (= 4 cols) per thread
  if (i >= n4) return;
  float4 v = ((const float4*)x)[i];
  int row = i >> 5;                                // 32 float4 per 128-col row
  float sc = dout_is[row];
  unsigned lo = (unsigned)f2bf(v.x * sc) | ((unsigned)f2bf(v.y * sc) << 16);
  unsigned hi = (unsigned)f2bf(v.z * sc) | ((unsigned)f2bf(v.w * sc) << 16);
  ((uint2*)xb2)[i] = make_uint2(lo, hi);
}

// ---------------- aggregation over bf16 rows (pre-scaled by dout), D=128 ----------------
// out[d] = din[d] * sum_{e in row d} hb[col[e]]   (fp32 accumulate)
__global__ __launch_bounds__(256) void agg128_bf16_kernel(
    const unsigned* __restrict__ hb,   // N x 64 dwords of bf16x2
    const int* __restrict__ rp, const int* __restrict__ col,
    const float* __restrict__ din_is, float* __restrict__ out, int N) {
  int wid  = (blockIdx.x * blockDim.x + threadIdx.x) >> 6;  // one wave per dst node
  int lane = threadIdx.x & 63;
  if (wid >= N) return;
  int s0 = rp[wid], s1 = rp[wid+1];
  float ax = 0.f, ay = 0.f;
  int e = s0;
  for (; e + 4 <= s1; e += 4) {       // 4 independent row loads in flight
    int c0 = col[e], c1 = col[e+1], c2 = col[e+2], c3 = col[e+3];
    unsigned v0 = hb[(size_t)c0*64 + lane];
    unsigned v1 = hb[(size_t)c1*64 + lane];
    unsigned v2 = hb[(size_t)c2*64 + lane];
    unsigned v3 = hb[(size_t)c3*64 + lane];
    float2 f0 = bfp2f2(v0), f1 = bfp2f2(v1), f2 = bfp2f2(v2), f3 = bfp2f2(v3);
    ax += (f0.x + f1.x) + (f2.x + f3.x);
    ay += (f0.y + f1.y) + (f2.y + f3.y);
  }
  for (; e < s1; ++e) {
    unsigned v = hb[(size_t)col[e]*64 + lane];
    float2 f = bfp2f2(v);
    ax += f.x; ay += f.y;
  }
  float di = din_is[wid];
  ((float2*)out)[(size_t)wid*64 + lane] = make_float2(ax*di, ay*di);
}

// ---------------- GEMM: Out[N,F] = A[N,128] @ W[128,F] (+bias), in-place safe ----------------
// BF16OUT: write bf16 rows scaled by rowscale[row] (for the gather that follows)
template<int F, int TX, int CPT, int RPT, bool BF16OUT>
__global__ __launch_bounds__(256) void gemm_kernel(
    const float* __restrict__ A, const float* __restrict__ W, const float* __restrict__ bias,
    float* __restrict__ Out, unsigned short* __restrict__ OutB,
    const float* __restrict__ rowscale, int N, int ntiles) {
  static_assert(TX*CPT == F, "cols");
  static_assert((256/TX)*RPT == 64, "rows");
  __shared__ float As[64][132];       // 64 rows x 128 K (+pad)
  __shared__ float Ws[32*F];          // K-chunk of W
  int tid = threadIdx.x;
  int tx = tid % TX;
  int ty = tid / TX;
  for (int tile = blockIdx.x; tile < ntiles; tile += gridDim.x) {
    int row0 = tile * 64;
    float acc[RPT][CPT];
    #pragma unroll
    for (int r=0;r<RPT;r++)
      #pragma unroll
      for (int j=0;j<CPT;j++) acc[r][j] = 0.f;
    __syncthreads();   // protect As/Ws from previous tile's readers
    #pragma unroll
    for (int i=0;i<8;i++){
      int idx = tid + i*256;          // 2048 float4 slots
      int r = idx >> 5;
      int c = (idx & 31) << 2;
      float4 v = make_float4(0.f,0.f,0.f,0.f);
      int gr = row0 + r;
      if (gr < N) v = *(const float4*)(A + (size_t)gr*128 + c);
      *(float4*)(&As[r][c]) = v;
    }
    for (int kc=0; kc<128; kc+=32) {
      __syncthreads();
      for (int i = tid; i < 32*F/4; i += 256)
        ((float4*)Ws)[i] = ((const float4*)(W + (size_t)kc*F))[i];
      __syncthreads();
      #pragma unroll 4
      for (int k=0;k<32;k++){
        float a[RPT];
        #pragma unroll
        for (int r=0;r<RPT;r++) a[r] = As[ty*RPT + r][kc + k];
        float b[CPT];
        #pragma unroll
        for (int j=0;j<CPT;j++) b[j] = Ws[k*F + tx*CPT + j];
        #pragma unroll
        for (int r=0;r<RPT;r++)
          #pragma unroll
          for (int j=0;j<CPT;j++)
            acc[r][j] += a[r]*b[j];
      }
    }
    #pragma unroll
    for (int r=0;r<RPT;r++){
      int gr = row0 + ty*RPT + r;
      if (gr < N){
        float sc = BF16OUT ? rowscale[gr] : 1.0f;
        #pragma unroll
        for (int j=0;j<CPT;j++){
          int c = tx*CPT + j;
          float v = acc[r][j];
          if (bias) v += bias[c];
          if (BF16OUT) OutB[(size_t)gr*F + c] = f2bf(v * sc);
          else         Out [(size_t)gr*F + c] = v;
        }
      }
    }
  }
}

// ---------------- BatchNorm ----------------
__global__ void bn_reduce_kernel(const float* __restrict__ h, float* __restrict__ gsum,
                                 float* __restrict__ gsumsq, int N, int rpb) {
  int f = threadIdx.x;                 // 128 threads = 128 cols
  int r0 = blockIdx.x * rpb;
  int r1 = r0 + rpb; if (r1 > N) r1 = N;
  float s = 0.f, ss = 0.f;
  for (int r = r0; r < r1; ++r) {
    float v = h[(size_t)r*128 + f];
    s += v; ss += v*v;
  }
  atomicAdd(&gsum[f], s);
  atomicAdd(&gsumsq[f], ss);
}

__global__ void bn_params_kernel(const float* __restrict__ gsum, const float* __restrict__ gsumsq,
                                 const float* __restrict__ g, const float* __restrict__ be,
                                 float* __restrict__ colA, float* __restrict__ colB, float invN) {
  int f = threadIdx.x;
  float mu  = gsum[f] * invN;
  float var = gsumsq[f] * invN - mu*mu;
  if (var < 0.f) var = 0.f;
  float rs = rsqrtf(var + 1e-5f);
  float a = g[f] * rs;
  colA[f] = a;
  colB[f] = be[f] - mu*a;
}

// fp32 out (feeds fp32 GEMM)
__global__ void bn_apply_kernel(const float* __restrict__ raw, const float* __restrict__ colA,
                                const float* __restrict__ colB, float* __restrict__ out, int n4) {
  int i = blockIdx.x * blockDim.x + threadIdx.x;
  if (i >= n4) return;
  float4 v = ((const float4*)raw)[i];
  int c4 = i & 31;                     // D=128 -> 32 float4 per row
  float4 a = ((const float4*)colA)[c4];
  float4 b = ((const float4*)colB)[c4];
  v.x = fmaxf(v.x*a.x + b.x, 0.f);
  v.y = fmaxf(v.y*a.y + b.y, 0.f);
  v.z = fmaxf(v.z*a.z + b.z, 0.f);
  v.w = fmaxf(v.w*a.w + b.w, 0.f);
  ((float4*)out)[i] = v;
}

// bf16 out, pre-scaled by dout_is (feeds the next gather)
__global__ void bn_apply_bf16_kernel(const float* __restrict__ raw, const float* __restrict__ colA,
                                     const float* __restrict__ colB, const float* __restrict__ dout_is,
                                     unsigned* __restrict__ outb, int n4) {
  int i = blockIdx.x * blockDim.x + threadIdx.x;
  if (i >= n4) return;
  float4 v = ((const float4*)raw)[i];
  int c4 = i & 31;
  int row = i >> 5;
  float sc = dout_is[row];
  float4 a = ((const float4*)colA)[c4];
  float4 b = ((const float4*)colB)[c4];
  float x0 = fmaxf(v.x*a.x + b.x, 0.f) * sc;
  float x1 = fmaxf(v.y*a.y + b.y, 0.f) * sc;
  float x2 = fmaxf(v.z*a.z + b.z, 0.f) * sc;
  float x3 = fmaxf(v.w*a.w + b.w, 0.f) * sc;
  unsigned lo = (unsigned)f2bf(x0) | ((unsigned)f2bf(x1) << 16);
  unsigned hi = (unsigned)f2bf(x2) | ((unsigned)f2bf(x3) << 16);
  ((uint2*)outb)[i] = make_uint2(lo, hi);
}

// ---------------- layer 3: aggregate 40-dim bf16 (pre-scaled) + bias + log_softmax ----------------
__global__ __launch_bounds__(256) void final_kernel(
    const unsigned short* __restrict__ tb, const int* __restrict__ rp, const int* __restrict__ col,
    const float* __restrict__ din_is, const float* __restrict__ b3,
    float* __restrict__ out, int N, int C) {
  int wid  = (blockIdx.x * blockDim.x + threadIdx.x) >> 6;
  int lane = threadIdx.x & 63;
  if (wid >= N) return;
  int lf = lane < C ? lane : C-1;
  int s0 = rp[wid], s1 = rp[wid+1];
  float acc = 0.f;
  int e = s0;
  for (; e + 4 <= s1; e += 4) {
    int c0 = col[e], c1 = col[e+1], c2 = col[e+2], c3 = col[e+3];
    unsigned short u0 = tb[(size_t)c0*C + lf];
    unsigned short u1 = tb[(size_t)c1*C + lf];
    unsigned short u2 = tb[(size_t)c2*C + lf];
    unsigned short u3 = tb[(size_t)c3*C + lf];
    acc += (bf2f(u0) + bf2f(u1)) + (bf2f(u2) + bf2f(u3));
  }
  for (; e < s1; ++e) acc += bf2f(tb[(size_t)col[e]*C + lf]);
  float z = (lane < C) ? din_is[wid]*acc + b3[lf] : -1e30f;
  float m = z;
  #pragma unroll
  for (int off=32; off>0; off>>=1) m = fmaxf(m, __shfl_xor(m, off));
  float ex = expf(z - m);
  float sum = ex;
  #pragma unroll
  for (int off=32; off>0; off>>=1) sum += __shfl_xor(sum, off);
  if (lane < C) out[(size_t)wid*C + lane] = z - m - logf(sum);
}

// ---------------- host ----------------
extern "C" void kernel_launch(void* const* d_in, const int* in_sizes, int n_in,
                              void* d_out, int out_size, void* d_ws, size_t ws_size,
                              hipStream_t stream) {
  const float* x   = (const float*)d_in[0];
  const int*   src = (const int*)d_in[1];
  const int*   dst = (const int*)d_in[2];
  const float* W1  = (const float*)d_in[3];
  const float* b1  = (const float*)d_in[4];
  const float* g1  = (const float*)d_in[5];
  const float* be1 = (const float*)d_in[6];
  const float* W2  = (const float*)d_in[7];
  const float* b2  = (const float*)d_in[8];
  const float* g2  = (const float*)d_in[9];
  const float* be2 = (const float*)d_in[10];
  const float* W3  = (const float*)d_in[11];
  const float* b3  = (const float*)d_in[12];
  const int E = in_sizes[1];
  const int D = in_sizes[4];     // 128
  const int C = in_sizes[12];    // 40
  const int N = in_sizes[0] / D; // 100000
  float* out = (float*)d_out;

  char* p = (char*)d_ws;
  auto alloc = [&](size_t bytes) { char* q = p; p += (bytes + 255) & ~(size_t)255; return q; };
  int* rp        = (int*)alloc((size_t)(N+1)*4);
  int* cursor    = (int*)alloc((size_t)N*4);
  int* cnt_in    = (int*)alloc((size_t)N*4);
  int* cnt_out   = (int*)alloc((size_t)N*4);
  int* bsum      = (int*)alloc(256*4);
  int* boff      = (int*)alloc(256*4);
  float* din_is  = (float*)alloc((size_t)N*4);
  float* dout_is = (float*)alloc((size_t)N*4);
  float* gsum    = (float*)alloc((size_t)D*4);
  float* gsumsq  = (float*)alloc((size_t)D*4);
  float* colA    = (float*)alloc((size_t)D*4);
  float* colB    = (float*)alloc((size_t)D*4);
  int*   col     = (int*)alloc((size_t)E*4);
  float* bufA    = (float*)alloc((size_t)N*D*4);
  float* bufB    = (float*)alloc((size_t)N*D*4);
  // bf16 buffer reused three times: xb (layer1 gather src), hb (layer2 gather src),
  // tb (layer3 gather src, N x C) — lifetimes are disjoint.
  unsigned* bf16buf = (unsigned*)alloc((size_t)N*D*2);

  hipMemsetAsync(cnt_in, 0, (size_t)N*4, stream);
  hipMemsetAsync(cnt_out, 0, (size_t)N*4, stream);
  int eb  = (E + 255)/256;
  int nbN = (N + 255)/256;
  hist_kernel<<<eb, 256, 0, stream>>>(src, dst, cnt_in, cnt_out, E);
  invsqrt_kernel<<<nbN, 256, 0, stream>>>(cnt_in, cnt_out, din_is, dout_is, N);
  int nb = (N + 1023)/1024;
  scan1_kernel<<<nb, 256, 0, stream>>>(cnt_in, rp, bsum, N);
  scan2_kernel<<<1, 256, 0, stream>>>(bsum, boff, nb);
  scan3_kernel<<<nbN, 256, 0, stream>>>(rp, cursor, boff, N, E);
  scatter_kernel<<<eb, 256, 0, stream>>>(src, dst, cursor, col, E);

  int aggb   = (N + 3)/4;          // 4 waves (nodes) per block
  int ntiles = (N + 63)/64;
  const int gemmGrid = 512;
  int rpb  = (N + 511)/512;
  int nel4 = (N*D)/4;

  // layer 1
  cast_scale_kernel<<<(nel4+255)/256, 256, 0, stream>>>(x, dout_is, bf16buf, nel4);
  agg128_bf16_kernel<<<aggb, 256, 0, stream>>>(bf16buf, rp, col, din_is, bufA, N);
  gemm_kernel<128,16,8,4,false><<<gemmGrid, 256, 0, stream>>>(bufA, W1, b1, bufA, nullptr, nullptr, N, ntiles);
  hipMemsetAsync(gsum, 0, (size_t)D*4, stream);
  hipMemsetAsync(gsumsq, 0, (size_t)D*4, stream);
  bn_reduce_kernel<<<512, 128, 0, stream>>>(bufA, gsum, gsumsq, N, rpb);
  bn_params_kernel<<<1, 128, 0, stream>>>(gsum, gsumsq, g1, be1, colA, colB, 1.0f/(float)N);
  bn_apply_bf16_kernel<<<(nel4+255)/256, 256, 0, stream>>>(bufA, colA, colB, dout_is, bf16buf, nel4);

  // layer 2
  agg128_bf16_kernel<<<aggb, 256, 0, stream>>>(bf16buf, rp, col, din_is, bufB, N);
  gemm_kernel<128,16,8,4,false><<<gemmGrid, 256, 0, stream>>>(bufB, W2, b2, bufB, nullptr, nullptr, N, ntiles);
  hipMemsetAsync(gsum, 0, (size_t)D*4, stream);
  hipMemsetAsync(gsumsq, 0, (size_t)D*4, stream);
  bn_reduce_kernel<<<512, 128, 0, stream>>>(bufB, gsum, gsumsq, N, rpb);
  bn_params_kernel<<<1, 128, 0, stream>>>(gsum, gsumsq, g2, be2, colA, colB, 1.0f/(float)N);
  bn_apply_kernel<<<(nel4+255)/256, 256, 0, stream>>>(bufB, colA, colB, bufA, nel4);

  // layer 3 (reordered: GEMM to 40 dims first — output bf16 pre-scaled by dout — then agg + softmax)
  gemm_kernel<40,8,5,2,true><<<gemmGrid, 256, 0, stream>>>(bufA, W3, nullptr, nullptr,
                                                           (unsigned short*)bf16buf, dout_is, N, ntiles);
  final_kernel<<<aggb, 256, 0, stream>>>((const unsigned short*)bf16buf, rp, col, din_is, b3, out, N, C);
}

// Round 3
// 981.057 us; speedup vs baseline: 1.2847x; 1.0192x over previous
//
#include <hip/hip_runtime.h>
#include <math.h>

// ---------- bf16 helpers ----------
__device__ inline unsigned short f2bf(float f) {
  union { float f; unsigned u; } v; v.f = f;
  unsigned r = v.u + 0x7fffu + ((v.u >> 16) & 1u);   // round-to-nearest-even
  return (unsigned short)(r >> 16);
}
__device__ inline float bf2f(unsigned short u) {
  union { unsigned u; float f; } v; v.u = ((unsigned)u) << 16;
  return v.f;
}
__device__ inline float2 bfp2f2(unsigned u) {       // packed bf16x2 -> float2
  union { unsigned u; float f; } a, b;
  a.u = u << 16;
  b.u = u & 0xffff0000u;
  float2 r; r.x = a.f; r.y = b.f; return r;
}

// ---------------- CSR build ----------------
__global__ void hist_kernel(const int* __restrict__ src, const int* __restrict__ dst,
                            int* __restrict__ cnt_in, int* __restrict__ cnt_out, int E) {
  int i = (blockIdx.x * blockDim.x + threadIdx.x) * 4;
  if (i + 4 <= E) {
    int s0=src[i], s1=src[i+1], s2=src[i+2], s3=src[i+3];
    int d0=dst[i], d1=dst[i+1], d2=dst[i+2], d3=dst[i+3];
    atomicAdd(&cnt_out[s0], 1); atomicAdd(&cnt_out[s1], 1);
    atomicAdd(&cnt_out[s2], 1); atomicAdd(&cnt_out[s3], 1);
    atomicAdd(&cnt_in[d0], 1);  atomicAdd(&cnt_in[d1], 1);
    atomicAdd(&cnt_in[d2], 1);  atomicAdd(&cnt_in[d3], 1);
  } else {
    for (int e = i; e < E; ++e) {
      atomicAdd(&cnt_out[src[e]], 1);
      atomicAdd(&cnt_in[dst[e]], 1);
    }
  }
}

__global__ void invsqrt_kernel(const int* __restrict__ cin, const int* __restrict__ cout,
                               float* __restrict__ din_is, float* __restrict__ dout_is, int N) {
  int i = blockIdx.x * blockDim.x + threadIdx.x;
  if (i < N) {
    int a = cin[i];  if (a < 1) a = 1;
    int b = cout[i]; if (b < 1) b = 1;
    din_is[i]  = rsqrtf((float)a);
    dout_is[i] = rsqrtf((float)b);
  }
}

// exclusive scan, 1024 elements per block
__global__ void scan1_kernel(const int* __restrict__ cnt, int* __restrict__ out,
                             int* __restrict__ bsum, int N) {
  __shared__ int sh[256];
  int t = threadIdx.x;
  int base = blockIdx.x * 1024 + t * 4;
  int v0=0,v1=0,v2=0,v3=0;
  if (base+0 < N) v0 = cnt[base+0];
  if (base+1 < N) v1 = cnt[base+1];
  if (base+2 < N) v2 = cnt[base+2];
  if (base+3 < N) v3 = cnt[base+3];
  int s = v0+v1+v2+v3;
  sh[t] = s;
  __syncthreads();
  for (int off=1; off<256; off<<=1){
    int x = (t >= off) ? sh[t-off] : 0;
    __syncthreads();
    sh[t] += x;
    __syncthreads();
  }
  if (t == 255) bsum[blockIdx.x] = sh[255];
  int run = sh[t] - s;
  if (base+0 < N) out[base+0] = run; run += v0;
  if (base+1 < N) out[base+1] = run; run += v1;
  if (base+2 < N) out[base+2] = run; run += v2;
  if (base+3 < N) out[base+3] = run;
}

__global__ void scan2_kernel(const int* __restrict__ bsum, int* __restrict__ boff, int nb) {
  __shared__ int sh[256];
  int t = threadIdx.x;
  int v = (t < nb) ? bsum[t] : 0;
  sh[t] = v;
  __syncthreads();
  for (int off=1; off<256; off<<=1){
    int x = (t >= off) ? sh[t-off] : 0;
    __syncthreads();
    sh[t] += x;
    __syncthreads();
  }
  if (t < nb) boff[t] = sh[t] - v;
}

__global__ void scan3_kernel(int* __restrict__ rp, int* __restrict__ cursor,
                             const int* __restrict__ boff, int N, int E) {
  int i = blockIdx.x * blockDim.x + threadIdx.x;
  if (i < N) { int v = rp[i] + boff[i >> 10]; rp[i] = v; cursor[i] = v; }
  if (i == 0) rp[N] = E;
}

__global__ void scatter_kernel(const int* __restrict__ src, const int* __restrict__ dst,
                               int* __restrict__ cursor, int* __restrict__ col, int E) {
  int i = (blockIdx.x * blockDim.x + threadIdx.x) * 4;
  if (i + 4 <= E) {
    int d0=dst[i], d1=dst[i+1], d2=dst[i+2], d3=dst[i+3];
    int s0=src[i], s1=src[i+1], s2=src[i+2], s3=src[i+3];
    int p0 = atomicAdd(&cursor[d0], 1);
    int p1 = atomicAdd(&cursor[d1], 1);
    int p2 = atomicAdd(&cursor[d2], 1);
    int p3 = atomicAdd(&cursor[d3], 1);
    col[p0]=s0; col[p1]=s1; col[p2]=s2; col[p3]=s3;
  } else {
    for (int e = i; e < E; ++e) {
      int p = atomicAdd(&cursor[dst[e]], 1);
      col[p] = src[e];
    }
  }
}

// ---------------- cast x (fp32 row) -> bf16 row pre-scaled by dout_is ----------------
__global__ void cast_scale_kernel(const float* __restrict__ x, const float* __restrict__ dout_is,
                                  unsigned* __restrict__ xb2, int n4) {
  int i = blockIdx.x * blockDim.x + threadIdx.x;   // one float4 (= 4 cols) per thread
  if (i >= n4) return;
  float4 v = ((const float4*)x)[i];
  int row = i >> 5;                                // 32 float4 per 128-col row
  float sc = dout_is[row];
  unsigned lo = (unsigned)f2bf(v.x * sc) | ((unsigned)f2bf(v.y * sc) << 16);
  unsigned hi = (unsigned)f2bf(v.z * sc) | ((unsigned)f2bf(v.w * sc) << 16);
  ((uint2*)xb2)[i] = make_uint2(lo, hi);
}

// ---------------- aggregation over bf16 rows (pre-scaled by dout), D=128 ----------------
// Quarter-wave per dst row: 16 lanes x uint4 (16B) = 256B row. 4 dst/wave, x4 unroll
// -> 16 outstanding row-gathers per wave.
__device__ inline void acc8(float* a, uint4 v) {
  float2 f;
  f = bfp2f2(v.x); a[0]+=f.x; a[1]+=f.y;
  f = bfp2f2(v.y); a[2]+=f.x; a[3]+=f.y;
  f = bfp2f2(v.z); a[4]+=f.x; a[5]+=f.y;
  f = bfp2f2(v.w); a[6]+=f.x; a[7]+=f.y;
}

__global__ __launch_bounds__(256) void agg128_bf16_kernel(
    const uint4* __restrict__ hb4,   // N rows x 16 uint4 (128 bf16)
    const int* __restrict__ rp, const int* __restrict__ col,
    const float* __restrict__ din_is, float* __restrict__ out, int N) {
  int wave = (blockIdx.x * blockDim.x + threadIdx.x) >> 6;
  int lane = threadIdx.x & 63;
  int g = lane >> 4, j = lane & 15;
  int d = wave * 4 + g;
  if (d >= N) return;
  int s0 = rp[d], s1 = rp[d+1];
  float a[8] = {0.f,0.f,0.f,0.f,0.f,0.f,0.f,0.f};
  int e = s0;
  for (; e + 4 <= s1; e += 4) {
    int c0 = col[e], c1 = col[e+1], c2 = col[e+2], c3 = col[e+3];
    uint4 v0 = hb4[(size_t)c0*16 + j];
    uint4 v1 = hb4[(size_t)c1*16 + j];
    uint4 v2 = hb4[(size_t)c2*16 + j];
    uint4 v3 = hb4[(size_t)c3*16 + j];
    acc8(a, v0); acc8(a, v1); acc8(a, v2); acc8(a, v3);
  }
  for (; e < s1; ++e) {
    uint4 v = hb4[(size_t)col[e]*16 + j];
    acc8(a, v);
  }
  float di = din_is[d];
  float4 o0 = make_float4(a[0]*di, a[1]*di, a[2]*di, a[3]*di);
  float4 o1 = make_float4(a[4]*di, a[5]*di, a[6]*di, a[7]*di);
  float4* ob = (float4*)out + (size_t)d*32 + 2*j;
  ob[0] = o0;
  ob[1] = o1;
}

// ---------------- GEMM: Out[N,F] = A[N,128] @ W[128,F] (+bias), in-place safe ----------------
// BF16OUT: write bf16 rows scaled by rowscale[row] (for the gather that follows)
template<int F, int TX, int CPT, int RPT, bool BF16OUT>
__global__ __launch_bounds__(256) void gemm_kernel(
    const float* __restrict__ A, const float* __restrict__ W, const float* __restrict__ bias,
    float* __restrict__ Out, unsigned short* __restrict__ OutB,
    const float* __restrict__ rowscale, int N, int ntiles) {
  static_assert(TX*CPT == F, "cols");
  static_assert((256/TX)*RPT == 64, "rows");
  __shared__ float As[64][132];       // 64 rows x 128 K (+pad)
  __shared__ float Ws[32*F];          // K-chunk of W
  int tid = threadIdx.x;
  int tx = tid % TX;
  int ty = tid / TX;
  for (int tile = blockIdx.x; tile < ntiles; tile += gridDim.x) {
    int row0 = tile * 64;
    float acc[RPT][CPT];
    #pragma unroll
    for (int r=0;r<RPT;r++)
      #pragma unroll
      for (int j=0;j<CPT;j++) acc[r][j] = 0.f;
    __syncthreads();   // protect As/Ws from previous tile's readers
    #pragma unroll
    for (int i=0;i<8;i++){
      int idx = tid + i*256;          // 2048 float4 slots
      int r = idx >> 5;
      int c = (idx & 31) << 2;
      float4 v = make_float4(0.f,0.f,0.f,0.f);
      int gr = row0 + r;
      if (gr < N) v = *(const float4*)(A + (size_t)gr*128 + c);
      *(float4*)(&As[r][c]) = v;
    }
    for (int kc=0; kc<128; kc+=32) {
      __syncthreads();
      for (int i = tid; i < 32*F/4; i += 256)
        ((float4*)Ws)[i] = ((const float4*)(W + (size_t)kc*F))[i];
      __syncthreads();
      #pragma unroll 4
      for (int k=0;k<32;k++){
        float a[RPT];
        #pragma unroll
        for (int r=0;r<RPT;r++) a[r] = As[ty*RPT + r][kc + k];
        float b[CPT];
        #pragma unroll
        for (int j=0;j<CPT;j++) b[j] = Ws[k*F + tx*CPT + j];
        #pragma unroll
        for (int r=0;r<RPT;r++)
          #pragma unroll
          for (int j=0;j<CPT;j++)
            acc[r][j] += a[r]*b[j];
      }
    }
    #pragma unroll
    for (int r=0;r<RPT;r++){
      int gr = row0 + ty*RPT + r;
      if (gr < N){
        float sc = BF16OUT ? rowscale[gr] : 1.0f;
        #pragma unroll
        for (int j=0;j<CPT;j++){
          int c = tx*CPT + j;
          float v = acc[r][j];
          if (bias) v += bias[c];
          if (BF16OUT) OutB[(size_t)gr*F + c] = f2bf(v * sc);
          else         Out [(size_t)gr*F + c] = v;
        }
      }
    }
  }
}

// ---------------- BatchNorm ----------------
__global__ void bn_reduce_kernel(const float* __restrict__ h, float* __restrict__ gsum,
                                 float* __restrict__ gsumsq, int N, int rpb) {
  int f = threadIdx.x;                 // 128 threads = 128 cols
  int r0 = blockIdx.x * rpb;
  int r1 = r0 + rpb; if (r1 > N) r1 = N;
  float s = 0.f, ss = 0.f;
  for (int r = r0; r < r1; ++r) {
    float v = h[(size_t)r*128 + f];
    s += v; ss += v*v;
  }
  atomicAdd(&gsum[f], s);
  atomicAdd(&gsumsq[f], ss);
}

__global__ void bn_params_kernel(const float* __restrict__ gsum, const float* __restrict__ gsumsq,
                                 const float* __restrict__ g, const float* __restrict__ be,
                                 float* __restrict__ colA, float* __restrict__ colB, float invN) {
  int f = threadIdx.x;
  float mu  = gsum[f] * invN;
  float var = gsumsq[f] * invN - mu*mu;
  if (var < 0.f) var = 0.f;
  float rs = rsqrtf(var + 1e-5f);
  float a = g[f] * rs;
  colA[f] = a;
  colB[f] = be[f] - mu*a;
}

// fp32 out (feeds fp32 GEMM)
__global__ void bn_apply_kernel(const float* __restrict__ raw, const float* __restrict__ colA,
                                const float* __restrict__ colB, float* __restrict__ out, int n4) {
  int i = blockIdx.x * blockDim.x + threadIdx.x;
  if (i >= n4) return;
  float4 v = ((const float4*)raw)[i];
  int c4 = i & 31;                     // D=128 -> 32 float4 per row
  float4 a = ((const float4*)colA)[c4];
  float4 b = ((const float4*)colB)[c4];
  v.x = fmaxf(v.x*a.x + b.x, 0.f);
  v.y = fmaxf(v.y*a.y + b.y, 0.f);
  v.z = fmaxf(v.z*a.z + b.z, 0.f);
  v.w = fmaxf(v.w*a.w + b.w, 0.f);
  ((float4*)out)[i] = v;
}

// bf16 out, pre-scaled by dout_is (feeds the next gather)
__global__ void bn_apply_bf16_kernel(const float* __restrict__ raw, const float* __restrict__ colA,
                                     const float* __restrict__ colB, const float* __restrict__ dout_is,
                                     unsigned* __restrict__ outb, int n4) {
  int i = blockIdx.x * blockDim.x + threadIdx.x;
  if (i >= n4) return;
  float4 v = ((const float4*)raw)[i];
  int c4 = i & 31;
  int row = i >> 5;
  float sc = dout_is[row];
  float4 a = ((const float4*)colA)[c4];
  float4 b = ((const float4*)colB)[c4];
  float x0 = fmaxf(v.x*a.x + b.x, 0.f) * sc;
  float x1 = fmaxf(v.y*a.y + b.y, 0.f) * sc;
  float x2 = fmaxf(v.z*a.z + b.z, 0.f) * sc;
  float x3 = fmaxf(v.w*a.w + b.w, 0.f) * sc;
  unsigned lo = (unsigned)f2bf(x0) | ((unsigned)f2bf(x1) << 16);
  unsigned hi = (unsigned)f2bf(x2) | ((unsigned)f2bf(x3) << 16);
  ((uint2*)outb)[i] = make_uint2(lo, hi);
}

// ---------------- layer 3: aggregate 40-dim bf16 (pre-scaled) + bias + log_softmax ----------------
// Half-wave per dst row: lanes j<20 load dword j (2 bf16 each = 40 cols). 2 dst/wave, x4 unroll.
__global__ __launch_bounds__(256) void final_kernel(
    const unsigned* __restrict__ tb,   // N rows x 20 dwords (40 bf16)
    const int* __restrict__ rp, const int* __restrict__ col,
    const float* __restrict__ din_is, const float* __restrict__ b3,
    float* __restrict__ out, int N) {
  int wave = (blockIdx.x * blockDim.x + threadIdx.x) >> 6;
  int g = (threadIdx.x >> 5) & 1;
  int j = threadIdx.x & 31;
  int d = wave * 2 + g;
  if (d >= N) return;
  bool act = (j < 20);
  int s0 = rp[d], s1 = rp[d+1];
  float a0 = 0.f, a1 = 0.f;
  int e = s0;
  for (; e + 4 <= s1; e += 4) {
    int c0 = col[e], c1 = col[e+1], c2 = col[e+2], c3 = col[e+3];
    unsigned u0 = act ? tb[(size_t)c0*20 + j] : 0u;
    unsigned u1 = act ? tb[(size_t)c1*20 + j] : 0u;
    unsigned u2 = act ? tb[(size_t)c2*20 + j] : 0u;
    unsigned u3 = act ? tb[(size_t)c3*20 + j] : 0u;
    float2 f0 = bfp2f2(u0), f1 = bfp2f2(u1), f2 = bfp2f2(u2), f3 = bfp2f2(u3);
    a0 += (f0.x + f1.x) + (f2.x + f3.x);
    a1 += (f0.y + f1.y) + (f2.y + f3.y);
  }
  for (; e < s1; ++e) {
    unsigned u = act ? tb[(size_t)col[e]*20 + j] : 0u;
    float2 f = bfp2f2(u);
    a0 += f.x; a1 += f.y;
  }
  float di = din_is[d];
  float z0 = act ? di*a0 + b3[2*j]   : -1e30f;
  float z1 = act ? di*a1 + b3[2*j+1] : -1e30f;
  float m = fmaxf(z0, z1);
  #pragma unroll
  for (int off=16; off>0; off>>=1) m = fmaxf(m, __shfl_xor(m, off, 32));
  float s = act ? (expf(z0-m) + expf(z1-m)) : 0.f;
  #pragma unroll
  for (int off=16; off>0; off>>=1) s += __shfl_xor(s, off, 32);
  float lg = logf(s);
  if (act) {
    float2 o = make_float2(z0 - m - lg, z1 - m - lg);
    ((float2*)(out + (size_t)d*40))[j] = o;
  }
}

// ---------------- host ----------------
extern "C" void kernel_launch(void* const* d_in, const int* in_sizes, int n_in,
                              void* d_out, int out_size, void* d_ws, size_t ws_size,
                              hipStream_t stream) {
  const float* x   = (const float*)d_in[0];
  const int*   src = (const int*)d_in[1];
  const int*   dst = (const int*)d_in[2];
  const float* W1  = (const float*)d_in[3];
  const float* b1  = (const float*)d_in[4];
  const float* g1  = (const float*)d_in[5];
  const float* be1 = (const float*)d_in[6];
  const float* W2  = (const float*)d_in[7];
  const float* b2  = (const float*)d_in[8];
  const float* g2  = (const float*)d_in[9];
  const float* be2 = (const float*)d_in[10];
  const float* W3  = (const float*)d_in[11];
  const float* b3  = (const float*)d_in[12];
  const int E = in_sizes[1];
  const int D = in_sizes[4];     // 128
  const int C = in_sizes[12];    // 40
  const int N = in_sizes[0] / D; // 100000
  float* out = (float*)d_out;
  (void)C;

  char* p = (char*)d_ws;
  auto alloc = [&](size_t bytes) { char* q = p; p += (bytes + 255) & ~(size_t)255; return q; };
  int* rp        = (int*)alloc((size_t)(N+1)*4);
  int* cursor    = (int*)alloc((size_t)N*4);
  int* cnt_in    = (int*)alloc((size_t)N*4);
  int* cnt_out   = (int*)alloc((size_t)N*4);
  int* bsum      = (int*)alloc(256*4);
  int* boff      = (int*)alloc(256*4);
  float* din_is  = (float*)alloc((size_t)N*4);
  float* dout_is = (float*)alloc((size_t)N*4);
  float* gsum    = (float*)alloc((size_t)D*4);
  float* gsumsq  = (float*)alloc((size_t)D*4);
  float* colA    = (float*)alloc((size_t)D*4);
  float* colB    = (float*)alloc((size_t)D*4);
  int*   col     = (int*)alloc((size_t)E*4);
  float* bufA    = (float*)alloc((size_t)N*D*4);
  float* bufB    = (float*)alloc((size_t)N*D*4);
  // bf16 buffer reused three times: xb (layer1 gather src), hb (layer2 gather src),
  // tb (layer3 gather src, N x C) — lifetimes are disjoint.
  unsigned* bf16buf = (unsigned*)alloc((size_t)N*D*2);

  hipMemsetAsync(cnt_in, 0, (size_t)N*4, stream);
  hipMemsetAsync(cnt_out, 0, (size_t)N*4, stream);
  int eb4 = (E/4 + 255)/256 + 1;
  int nbN = (N + 255)/256;
  hist_kernel<<<eb4, 256, 0, stream>>>(src, dst, cnt_in, cnt_out, E);
  invsqrt_kernel<<<nbN, 256, 0, stream>>>(cnt_in, cnt_out, din_is, dout_is, N);
  int nb = (N + 1023)/1024;
  scan1_kernel<<<nb, 256, 0, stream>>>(cnt_in, rp, bsum, N);
  scan2_kernel<<<1, 256, 0, stream>>>(bsum, boff, nb);
  scan3_kernel<<<nbN, 256, 0, stream>>>(rp, cursor, boff, N, E);
  scatter_kernel<<<eb4, 256, 0, stream>>>(src, dst, cursor, col, E);

  int aggb   = ((N + 3)/4*64 + 255)/256;    // 4 dst per wave
  int finb   = ((N + 1)/2*64 + 255)/256;    // 2 dst per wave
  int ntiles = (N + 63)/64;
  const int gemmGrid = 512;
  int rpb  = (N + 511)/512;
  int nel4 = (N*D)/4;

  // layer 1
  cast_scale_kernel<<<(nel4+255)/256, 256, 0, stream>>>(x, dout_is, bf16buf, nel4);
  agg128_bf16_kernel<<<aggb, 256, 0, stream>>>((const uint4*)bf16buf, rp, col, din_is, bufA, N);
  gemm_kernel<128,16,8,4,false><<<gemmGrid, 256, 0, stream>>>(bufA, W1, b1, bufA, nullptr, nullptr, N, ntiles);
  hipMemsetAsync(gsum, 0, (size_t)D*4, stream);
  hipMemsetAsync(gsumsq, 0, (size_t)D*4, stream);
  bn_reduce_kernel<<<512, 128, 0, stream>>>(bufA, gsum, gsumsq, N, rpb);
  bn_params_kernel<<<1, 128, 0, stream>>>(gsum, gsumsq, g1, be1, colA, colB, 1.0f/(float)N);
  bn_apply_bf16_kernel<<<(nel4+255)/256, 256, 0, stream>>>(bufA, colA, colB, dout_is, bf16buf, nel4);

  // layer 2
  agg128_bf16_kernel<<<aggb, 256, 0, stream>>>((const uint4*)bf16buf, rp, col, din_is, bufB, N);
  gemm_kernel<128,16,8,4,false><<<gemmGrid, 256, 0, stream>>>(bufB, W2, b2, bufB, nullptr, nullptr, N, ntiles);
  hipMemsetAsync(gsum, 0, (size_t)D*4, stream);
  hipMemsetAsync(gsumsq, 0, (size_t)D*4, stream);
  bn_reduce_kernel<<<512, 128, 0, stream>>>(bufB, gsum, gsumsq, N, rpb);
  bn_params_kernel<<<1, 128, 0, stream>>>(gsum, gsumsq, g2, be2, colA, colB, 1.0f/(float)N);
  bn_apply_kernel<<<(nel4+255)/256, 256, 0, stream>>>(bufB, colA, colB, bufA, nel4);

  // layer 3 (reordered: GEMM to 40 dims first — output bf16 pre-scaled by dout — then agg + softmax)
  gemm_kernel<40,8,5,2,true><<<gemmGrid, 256, 0, stream>>>(bufA, W3, nullptr, nullptr,
                                                           (unsigned short*)bf16buf, dout_is, N, ntiles);
  final_kernel<<<finb, 256, 0, stream>>>((const unsigned*)bf16buf, rp, col, din_is, b3, out, N);
}

// Round 4
// 819.547 us; speedup vs baseline: 1.5379x; 1.1971x over previous
//
#include <hip/hip_runtime.h>
#include <math.h>

#define MAXNB 1024   // max buckets (N <= 262144 with 256 nodes/bucket)
#define BCH   8192   // edges per block in count/bin kernels
#define BCAP  16384  // per-bucket edge capacity in finalize (mean 4096)

// ---------- bf16 helpers ----------
__device__ inline unsigned short f2bf(float f) {
  union { float f; unsigned u; } v; v.f = f;
  unsigned r = v.u + 0x7fffu + ((v.u >> 16) & 1u);   // round-to-nearest-even
  return (unsigned short)(r >> 16);
}
__device__ inline float2 bfp2f2(unsigned u) {       // packed bf16x2 -> float2
  union { unsigned u; float f; } a, b;
  a.u = u << 16;
  b.u = u & 0xffff0000u;
  float2 r; r.x = a.f; r.y = b.f; return r;
}

// ---------------- CSR build: bucketed two-pass sort ----------------
// B1: per-block LDS histogram of dst buckets (+ global cnt_out histogram for src)
__global__ __launch_bounds__(256) void bucket_count_kernel(
    const int* __restrict__ src, const int* __restrict__ dst,
    int* __restrict__ bcnt, int* __restrict__ cnt_out, int E, int NB) {
  __shared__ int hist[MAXNB];
  int tid = threadIdx.x;
  for (int i = tid; i < MAXNB; i += 256) hist[i] = 0;
  __syncthreads();
  int e0 = blockIdx.x * BCH;
  #pragma unroll
  for (int k = 0; k < BCH/256; ++k) {
    int e = e0 + k*256 + tid;
    if (e < E) {
      atomicAdd(&hist[dst[e] >> 8], 1);
      atomicAdd(&cnt_out[src[e]], 1);      // out-degree (random, but only one array now)
    }
  }
  __syncthreads();
  for (int i = tid; i < NB; i += 256)
    if (hist[i]) atomicAdd(&bcnt[i], hist[i]);
}

// B2: scan bucket counts -> bbase[NB+1], init bcur, set rp[N]=E
__global__ __launch_bounds__(256) void bucket_scan_kernel(
    const int* __restrict__ bcnt, int* __restrict__ bbase, int* __restrict__ bcur,
    int* __restrict__ rp, int NB, int N, int E) {
  __shared__ int sh[256];
  int t = threadIdx.x;
  int base = t * 4;
  int v0 = (base+0 < NB) ? bcnt[base+0] : 0;
  int v1 = (base+1 < NB) ? bcnt[base+1] : 0;
  int v2 = (base+2 < NB) ? bcnt[base+2] : 0;
  int v3 = (base+3 < NB) ? bcnt[base+3] : 0;
  int s = v0+v1+v2+v3;
  sh[t] = s;
  __syncthreads();
  for (int off=1; off<256; off<<=1){
    int x = (t >= off) ? sh[t-off] : 0;
    __syncthreads();
    sh[t] += x;
    __syncthreads();
  }
  int run = sh[t] - s;
  if (base+0 <= NB) { bbase[base+0] = run; if (base+0 < NB) bcur[base+0] = run; } run += v0;
  if (base+1 <= NB) { bbase[base+1] = run; if (base+1 < NB) bcur[base+1] = run; } run += v1;
  if (base+2 <= NB) { bbase[base+2] = run; if (base+2 < NB) bcur[base+2] = run; } run += v2;
  if (base+3 <= NB) { bbase[base+3] = run; if (base+3 < NB) bcur[base+3] = run; }
  if (t == 0) rp[N] = E;
}

// B3: bin edges into bucket-grouped ebuf via LDS staging (coalesced run flush)
__global__ __launch_bounds__(256) void bin_kernel(
    const int* __restrict__ src, const int* __restrict__ dst,
    int* __restrict__ bcur, uint2* __restrict__ ebuf, int E, int NB) {
  __shared__ int hist[MAXNB];
  __shared__ int scanb[MAXNB];
  __shared__ int rbase[MAXNB];
  __shared__ int lcur[MAXNB];
  __shared__ int tmp[256];
  __shared__ uint2 stage[BCH];
  int tid = threadIdx.x;
  int e0 = blockIdx.x * BCH;
  int nedge = E - e0; if (nedge > BCH) nedge = BCH; if (nedge < 0) nedge = 0;
  for (int i = tid; i < MAXNB; i += 256) hist[i] = 0;
  __syncthreads();
  // pass 1: histogram
  #pragma unroll
  for (int k = 0; k < BCH/256; ++k) {
    int e = e0 + k*256 + tid;
    if (e < E) atomicAdd(&hist[dst[e] >> 8], 1);
  }
  __syncthreads();
  // scan (groups of 4 per thread over MAXNB)
  {
    int base = tid * 4;
    int v0 = hist[base+0], v1 = hist[base+1], v2 = hist[base+2], v3 = hist[base+3];
    int s = v0+v1+v2+v3;
    tmp[tid] = s;
    __syncthreads();
    for (int off=1; off<256; off<<=1){
      int x = (tid >= off) ? tmp[tid-off] : 0;
      __syncthreads();
      tmp[tid] += x;
      __syncthreads();
    }
    int run = tmp[tid] - s;
    scanb[base+0] = run; run += v0;
    scanb[base+1] = run; run += v1;
    scanb[base+2] = run; run += v2;
    scanb[base+3] = run;
  }
  __syncthreads();
  // reserve global runs, init local cursors
  for (int i = tid; i < NB; i += 256) {
    int h = hist[i];
    rbase[i] = h ? atomicAdd(&bcur[i], h) : 0;
    lcur[i] = scanb[i];
  }
  __syncthreads();
  // pass 2: place into LDS grouped by bucket
  #pragma unroll
  for (int k = 0; k < BCH/256; ++k) {
    int e = e0 + k*256 + tid;
    if (e < E) {
      int d = dst[e];
      int b = d >> 8;
      int p = atomicAdd(&lcur[b], 1);
      stage[p] = make_uint2((unsigned)src[e], (unsigned)d);
    }
  }
  __syncthreads();
  // flush: consecutive LDS slots of a bucket -> consecutive global addresses
  for (int i = tid; i < nedge; i += 256) {
    uint2 ed = stage[i];
    int b = (int)(ed.y >> 8);
    ebuf[rbase[b] + (i - scanb[b])] = ed;
  }
}

// B4: per-bucket counting sort -> rp, din_is, col (coalesced)
__global__ __launch_bounds__(256) void finalize_kernel(
    const uint2* __restrict__ ebuf, const int* __restrict__ bbase,
    int* __restrict__ rp, float* __restrict__ din_is,
    int* __restrict__ col, int N) {
  __shared__ int lcnt[256];
  __shared__ int lrp[257];
  __shared__ int lcur[256];
  __shared__ int tmp[256];
  __shared__ int colbuf[BCAP];
  int b = blockIdx.x;
  int tid = threadIdx.x;
  int node0 = b << 8;
  int e0 = bbase[b], e1 = bbase[b+1];
  int ne = e1 - e0;
  lcnt[tid] = 0;
  __syncthreads();
  for (int i = tid; i < ne; i += 256)
    atomicAdd(&lcnt[ebuf[e0+i].y & 255], 1);
  __syncthreads();
  int c = lcnt[tid];
  tmp[tid] = c;
  __syncthreads();
  for (int off=1; off<256; off<<=1){
    int x = (tid >= off) ? tmp[tid-off] : 0;
    __syncthreads();
    tmp[tid] += x;
    __syncthreads();
  }
  lrp[tid] = tmp[tid] - c;
  lcur[tid] = tmp[tid] - c;
  if (tid == 255) lrp[256] = tmp[255];
  __syncthreads();
  int node = node0 + tid;
  if (node < N) {
    rp[node] = e0 + lrp[tid];
    int cc = c < 1 ? 1 : c;
    din_is[node] = rsqrtf((float)cc);
  }
  if (ne <= BCAP) {
    for (int i = tid; i < ne; i += 256) {
      uint2 ed = ebuf[e0+i];
      int p = atomicAdd(&lcur[ed.y & 255], 1);
      colbuf[p] = (int)ed.x;
    }
    __syncthreads();
    for (int i = tid; i < ne; i += 256) col[e0+i] = colbuf[i];
  } else {  // overflow fallback (never expected at this E/N)
    for (int i = tid; i < ne; i += 256) {
      uint2 ed = ebuf[e0+i];
      int p = atomicAdd(&lcur[ed.y & 255], 1);
      col[e0+p] = (int)ed.x;
    }
  }
}

__global__ void invsqrt_dout_kernel(const int* __restrict__ cout,
                                    float* __restrict__ dout_is, int N) {
  int i = blockIdx.x * blockDim.x + threadIdx.x;
  if (i < N) {
    int b = cout[i]; if (b < 1) b = 1;
    dout_is[i] = rsqrtf((float)b);
  }
}

// ---------------- cast x (fp32 row) -> bf16 row pre-scaled by dout_is ----------------
__global__ void cast_scale_kernel(const float* __restrict__ x, const float* __restrict__ dout_is,
                                  unsigned* __restrict__ xb2, int n4) {
  int i = blockIdx.x * blockDim.x + threadIdx.x;   // one float4 (= 4 cols) per thread
  if (i >= n4) return;
  float4 v = ((const float4*)x)[i];
  int row = i >> 5;                                // 32 float4 per 128-col row
  float sc = dout_is[row];
  unsigned lo = (unsigned)f2bf(v.x * sc) | ((unsigned)f2bf(v.y * sc) << 16);
  unsigned hi = (unsigned)f2bf(v.z * sc) | ((unsigned)f2bf(v.w * sc) << 16);
  ((uint2*)xb2)[i] = make_uint2(lo, hi);
}

// ---------------- aggregation over bf16 rows (pre-scaled by dout), D=128 ----------------
// Quarter-wave per dst row: 16 lanes x uint4 (16B) = 256B row. 4 dst/wave, x4 unroll.
__device__ inline void acc8(float* a, uint4 v) {
  float2 f;
  f = bfp2f2(v.x); a[0]+=f.x; a[1]+=f.y;
  f = bfp2f2(v.y); a[2]+=f.x; a[3]+=f.y;
  f = bfp2f2(v.z); a[4]+=f.x; a[5]+=f.y;
  f = bfp2f2(v.w); a[6]+=f.x; a[7]+=f.y;
}

__global__ __launch_bounds__(256) void agg128_bf16_kernel(
    const uint4* __restrict__ hb4,   // N rows x 16 uint4 (128 bf16)
    const int* __restrict__ rp, const int* __restrict__ col,
    const float* __restrict__ din_is, float* __restrict__ out, int N) {
  int wave = (blockIdx.x * blockDim.x + threadIdx.x) >> 6;
  int lane = threadIdx.x & 63;
  int g = lane >> 4, j = lane & 15;
  int d = wave * 4 + g;
  if (d >= N) return;
  int s0 = rp[d], s1 = rp[d+1];
  float a[8] = {0.f,0.f,0.f,0.f,0.f,0.f,0.f,0.f};
  int e = s0;
  for (; e + 4 <= s1; e += 4) {
    int c0 = col[e], c1 = col[e+1], c2 = col[e+2], c3 = col[e+3];
    uint4 v0 = hb4[(size_t)c0*16 + j];
    uint4 v1 = hb4[(size_t)c1*16 + j];
    uint4 v2 = hb4[(size_t)c2*16 + j];
    uint4 v3 = hb4[(size_t)c3*16 + j];
    acc8(a, v0); acc8(a, v1); acc8(a, v2); acc8(a, v3);
  }
  for (; e < s1; ++e) {
    uint4 v = hb4[(size_t)col[e]*16 + j];
    acc8(a, v);
  }
  float di = din_is[d];
  float4 o0 = make_float4(a[0]*di, a[1]*di, a[2]*di, a[3]*di);
  float4 o1 = make_float4(a[4]*di, a[5]*di, a[6]*di, a[7]*di);
  float4* ob = (float4*)out + (size_t)d*32 + 2*j;
  ob[0] = o0;
  ob[1] = o1;
}

// ---------------- GEMM: Out[N,F] = A[N,128] @ W[128,F] (+bias), in-place safe ----------------
template<int F, int TX, int CPT, int RPT, bool BF16OUT>
__global__ __launch_bounds__(256) void gemm_kernel(
    const float* __restrict__ A, const float* __restrict__ W, const float* __restrict__ bias,
    float* __restrict__ Out, unsigned short* __restrict__ OutB,
    const float* __restrict__ rowscale, int N, int ntiles) {
  static_assert(TX*CPT == F, "cols");
  static_assert((256/TX)*RPT == 64, "rows");
  __shared__ float As[64][132];
  __shared__ float Ws[32*F];
  int tid = threadIdx.x;
  int tx = tid % TX;
  int ty = tid / TX;
  for (int tile = blockIdx.x; tile < ntiles; tile += gridDim.x) {
    int row0 = tile * 64;
    float acc[RPT][CPT];
    #pragma unroll
    for (int r=0;r<RPT;r++)
      #pragma unroll
      for (int j=0;j<CPT;j++) acc[r][j] = 0.f;
    __syncthreads();
    #pragma unroll
    for (int i=0;i<8;i++){
      int idx = tid + i*256;
      int r = idx >> 5;
      int c = (idx & 31) << 2;
      float4 v = make_float4(0.f,0.f,0.f,0.f);
      int gr = row0 + r;
      if (gr < N) v = *(const float4*)(A + (size_t)gr*128 + c);
      *(float4*)(&As[r][c]) = v;
    }
    for (int kc=0; kc<128; kc+=32) {
      __syncthreads();
      for (int i = tid; i < 32*F/4; i += 256)
        ((float4*)Ws)[i] = ((const float4*)(W + (size_t)kc*F))[i];
      __syncthreads();
      #pragma unroll 4
      for (int k=0;k<32;k++){
        float a[RPT];
        #pragma unroll
        for (int r=0;r<RPT;r++) a[r] = As[ty*RPT + r][kc + k];
        float b[CPT];
        #pragma unroll
        for (int j=0;j<CPT;j++) b[j] = Ws[k*F + tx*CPT + j];
        #pragma unroll
        for (int r=0;r<RPT;r++)
          #pragma unroll
          for (int j=0;j<CPT;j++)
            acc[r][j] += a[r]*b[j];
      }
    }
    #pragma unroll
    for (int r=0;r<RPT;r++){
      int gr = row0 + ty*RPT + r;
      if (gr < N){
        float sc = BF16OUT ? rowscale[gr] : 1.0f;
        #pragma unroll
        for (int j=0;j<CPT;j++){
          int c = tx*CPT + j;
          float v = acc[r][j];
          if (bias) v += bias[c];
          if (BF16OUT) OutB[(size_t)gr*F + c] = f2bf(v * sc);
          else         Out [(size_t)gr*F + c] = v;
        }
      }
    }
  }
}

// ---------------- BatchNorm ----------------
__global__ void bn_reduce_kernel(const float* __restrict__ h, float* __restrict__ gsum,
                                 float* __restrict__ gsumsq, int N, int rpb) {
  int f = threadIdx.x;
  int r0 = blockIdx.x * rpb;
  int r1 = r0 + rpb; if (r1 > N) r1 = N;
  float s = 0.f, ss = 0.f;
  for (int r = r0; r < r1; ++r) {
    float v = h[(size_t)r*128 + f];
    s += v; ss += v*v;
  }
  atomicAdd(&gsum[f], s);
  atomicAdd(&gsumsq[f], ss);
}

__global__ void bn_params_kernel(const float* __restrict__ gsum, const float* __restrict__ gsumsq,
                                 const float* __restrict__ g, const float* __restrict__ be,
                                 float* __restrict__ colA, float* __restrict__ colB, float invN) {
  int f = threadIdx.x;
  float mu  = gsum[f] * invN;
  float var = gsumsq[f] * invN - mu*mu;
  if (var < 0.f) var = 0.f;
  float rs = rsqrtf(var + 1e-5f);
  float a = g[f] * rs;
  colA[f] = a;
  colB[f] = be[f] - mu*a;
}

__global__ void bn_apply_kernel(const float* __restrict__ raw, const float* __restrict__ colA,
                                const float* __restrict__ colB, float* __restrict__ out, int n4) {
  int i = blockIdx.x * blockDim.x + threadIdx.x;
  if (i >= n4) return;
  float4 v = ((const float4*)raw)[i];
  int c4 = i & 31;
  float4 a = ((const float4*)colA)[c4];
  float4 b = ((const float4*)colB)[c4];
  v.x = fmaxf(v.x*a.x + b.x, 0.f);
  v.y = fmaxf(v.y*a.y + b.y, 0.f);
  v.z = fmaxf(v.z*a.z + b.z, 0.f);
  v.w = fmaxf(v.w*a.w + b.w, 0.f);
  ((float4*)out)[i] = v;
}

__global__ void bn_apply_bf16_kernel(const float* __restrict__ raw, const float* __restrict__ colA,
                                     const float* __restrict__ colB, const float* __restrict__ dout_is,
                                     unsigned* __restrict__ outb, int n4) {
  int i = blockIdx.x * blockDim.x + threadIdx.x;
  if (i >= n4) return;
  float4 v = ((const float4*)raw)[i];
  int c4 = i & 31;
  int row = i >> 5;
  float sc = dout_is[row];
  float4 a = ((const float4*)colA)[c4];
  float4 b = ((const float4*)colB)[c4];
  float x0 = fmaxf(v.x*a.x + b.x, 0.f) * sc;
  float x1 = fmaxf(v.y*a.y + b.y, 0.f) * sc;
  float x2 = fmaxf(v.z*a.z + b.z, 0.f) * sc;
  float x3 = fmaxf(v.w*a.w + b.w, 0.f) * sc;
  unsigned lo = (unsigned)f2bf(x0) | ((unsigned)f2bf(x1) << 16);
  unsigned hi = (unsigned)f2bf(x2) | ((unsigned)f2bf(x3) << 16);
  ((uint2*)outb)[i] = make_uint2(lo, hi);
}

// ---------------- layer 3: aggregate 40-dim bf16 (pre-scaled) + bias + log_softmax ----------------
__global__ __launch_bounds__(256) void final_kernel(
    const unsigned* __restrict__ tb,   // N rows x 20 dwords (40 bf16)
    const int* __restrict__ rp, const int* __restrict__ col,
    const float* __restrict__ din_is, const float* __restrict__ b3,
    float* __restrict__ out, int N) {
  int wave = (blockIdx.x * blockDim.x + threadIdx.x) >> 6;
  int g = (threadIdx.x >> 5) & 1;
  int j = threadIdx.x & 31;
  int d = wave * 2 + g;
  if (d >= N) return;
  bool act = (j < 20);
  int s0 = rp[d], s1 = rp[d+1];
  float a0 = 0.f, a1 = 0.f;
  int e = s0;
  for (; e + 4 <= s1; e += 4) {
    int c0 = col[e], c1 = col[e+1], c2 = col[e+2], c3 = col[e+3];
    unsigned u0 = act ? tb[(size_t)c0*20 + j] : 0u;
    unsigned u1 = act ? tb[(size_t)c1*20 + j] : 0u;
    unsigned u2 = act ? tb[(size_t)c2*20 + j] : 0u;
    unsigned u3 = act ? tb[(size_t)c3*20 + j] : 0u;
    float2 f0 = bfp2f2(u0), f1 = bfp2f2(u1), f2 = bfp2f2(u2), f3 = bfp2f2(u3);
    a0 += (f0.x + f1.x) + (f2.x + f3.x);
    a1 += (f0.y + f1.y) + (f2.y + f3.y);
  }
  for (; e < s1; ++e) {
    unsigned u = act ? tb[(size_t)col[e]*20 + j] : 0u;
    float2 f = bfp2f2(u);
    a0 += f.x; a1 += f.y;
  }
  float di = din_is[d];
  float z0 = act ? di*a0 + b3[2*j]   : -1e30f;
  float z1 = act ? di*a1 + b3[2*j+1] : -1e30f;
  float m = fmaxf(z0, z1);
  #pragma unroll
  for (int off=16; off>0; off>>=1) m = fmaxf(m, __shfl_xor(m, off, 32));
  float s = act ? (expf(z0-m) + expf(z1-m)) : 0.f;
  #pragma unroll
  for (int off=16; off>0; off>>=1) s += __shfl_xor(s, off, 32);
  float lg = logf(s);
  if (act) {
    float2 o = make_float2(z0 - m - lg, z1 - m - lg);
    ((float2*)(out + (size_t)d*40))[j] = o;
  }
}

// ---------------- host ----------------
extern "C" void kernel_launch(void* const* d_in, const int* in_sizes, int n_in,
                              void* d_out, int out_size, void* d_ws, size_t ws_size,
                              hipStream_t stream) {
  const float* x   = (const float*)d_in[0];
  const int*   src = (const int*)d_in[1];
  const int*   dst = (const int*)d_in[2];
  const float* W1  = (const float*)d_in[3];
  const float* b1  = (const float*)d_in[4];
  const float* g1  = (const float*)d_in[5];
  const float* be1 = (const float*)d_in[6];
  const float* W2  = (const float*)d_in[7];
  const float* b2  = (const float*)d_in[8];
  const float* g2  = (const float*)d_in[9];
  const float* be2 = (const float*)d_in[10];
  const float* W3  = (const float*)d_in[11];
  const float* b3  = (const float*)d_in[12];
  const int E = in_sizes[1];
  const int D = in_sizes[4];     // 128
  const int N = in_sizes[0] / D; // 100000
  float* out = (float*)d_out;

  char* p = (char*)d_ws;
  auto alloc = [&](size_t bytes) { char* q = p; p += (bytes + 255) & ~(size_t)255; return q; };
  int* rp        = (int*)alloc((size_t)(N+1)*4);
  int* cnt_out   = (int*)alloc((size_t)N*4);
  float* din_is  = (float*)alloc((size_t)N*4);
  float* dout_is = (float*)alloc((size_t)N*4);
  float* gsum    = (float*)alloc((size_t)D*4);
  float* gsumsq  = (float*)alloc((size_t)D*4);
  float* colA    = (float*)alloc((size_t)D*4);
  float* colB    = (float*)alloc((size_t)D*4);
  int* bcnt      = (int*)alloc((size_t)MAXNB*4);
  int* bbase     = (int*)alloc((size_t)(MAXNB+1)*4);
  int* bcur      = (int*)alloc((size_t)MAXNB*4);
  int*   col     = (int*)alloc((size_t)E*4);
  float* bufA    = (float*)alloc((size_t)N*D*4);
  float* bufB    = (float*)alloc((size_t)N*D*4);
  unsigned* bf16buf = (unsigned*)alloc((size_t)N*D*2);
  // ebuf aliases bufA: CSR build finishes before bufA's first write (layer-1 agg output)
  uint2* ebuf = (uint2*)bufA;

  const int NB = (N + 255) >> 8;   // 391 buckets of 256 nodes
  int nbN = (N + 255)/256;
  int ebB = (E + BCH - 1)/BCH;     // 196 blocks

  hipMemsetAsync(cnt_out, 0, (size_t)N*4, stream);
  hipMemsetAsync(bcnt, 0, (size_t)MAXNB*4, stream);
  bucket_count_kernel<<<ebB, 256, 0, stream>>>(src, dst, bcnt, cnt_out, E, NB);
  invsqrt_dout_kernel<<<nbN, 256, 0, stream>>>(cnt_out, dout_is, N);
  bucket_scan_kernel<<<1, 256, 0, stream>>>(bcnt, bbase, bcur, rp, NB, N, E);
  bin_kernel<<<ebB, 256, 0, stream>>>(src, dst, bcur, ebuf, E, NB);
  finalize_kernel<<<NB, 256, 0, stream>>>(ebuf, bbase, rp, din_is, col, N);

  int aggb   = ((N + 3)/4*64 + 255)/256;    // 4 dst per wave
  int finb   = ((N + 1)/2*64 + 255)/256;    // 2 dst per wave
  int ntiles = (N + 63)/64;
  const int gemmGrid = 512;
  int rpb  = (N + 511)/512;
  int nel4 = (N*D)/4;

  // layer 1
  cast_scale_kernel<<<(nel4+255)/256, 256, 0, stream>>>(x, dout_is, bf16buf, nel4);
  agg128_bf16_kernel<<<aggb, 256, 0, stream>>>((const uint4*)bf16buf, rp, col, din_is, bufA, N);
  gemm_kernel<128,16,8,4,false><<<gemmGrid, 256, 0, stream>>>(bufA, W1, b1, bufA, nullptr, nullptr, N, ntiles);
  hipMemsetAsync(gsum, 0, (size_t)D*4, stream);
  hipMemsetAsync(gsumsq, 0, (size_t)D*4, stream);
  bn_reduce_kernel<<<512, 128, 0, stream>>>(bufA, gsum, gsumsq, N, rpb);
  bn_params_kernel<<<1, 128, 0, stream>>>(gsum, gsumsq, g1, be1, colA, colB, 1.0f/(float)N);
  bn_apply_bf16_kernel<<<(nel4+255)/256, 256, 0, stream>>>(bufA, colA, colB, dout_is, bf16buf, nel4);

  // layer 2
  agg128_bf16_kernel<<<aggb, 256, 0, stream>>>((const uint4*)bf16buf, rp, col, din_is, bufB, N);
  gemm_kernel<128,16,8,4,false><<<gemmGrid, 256, 0, stream>>>(bufB, W2, b2, bufB, nullptr, nullptr, N, ntiles);
  hipMemsetAsync(gsum, 0, (size_t)D*4, stream);
  hipMemsetAsync(gsumsq, 0, (size_t)D*4, stream);
  bn_reduce_kernel<<<512, 128, 0, stream>>>(bufB, gsum, gsumsq, N, rpb);
  bn_params_kernel<<<1, 128, 0, stream>>>(gsum, gsumsq, g2, be2, colA, colB, 1.0f/(float)N);
  bn_apply_kernel<<<(nel4+255)/256, 256, 0, stream>>>(bufB, colA, colB, bufA, nel4);

  // layer 3 (GEMM to 40 dims first — bf16 out pre-scaled by dout — then agg + softmax)
  gemm_kernel<40,8,5,2,true><<<gemmGrid, 256, 0, stream>>>(bufA, W3, nullptr, nullptr,
                                                           (unsigned short*)bf16buf, dout_is, N, ntiles);
  final_kernel<<<finb, 256, 0, stream>>>((const unsigned*)bf16buf, rp, col, din_is, b3, out, N);
}

// Round 5
// 739.939 us; speedup vs baseline: 1.7034x; 1.1076x over previous
//
#include <hip/hip_runtime.h>
#include <math.h>

#define MAXNB 1024   // max buckets (N <= 262144 with 256 nodes/bucket)
#define BCH   8192   // edges per block in count/bin kernels
#define BCAP  16384  // per-bucket edge capacity in finalize (mean 4096)

typedef __attribute__((ext_vector_type(8))) __bf16 bf16x8;
typedef __attribute__((ext_vector_type(4))) float floatx4;

__device__ inline bf16x8 asbf(uint4 u) {
  union { uint4 u; bf16x8 b; } c; c.u = u; return c.b;
}

// ---------- bf16 helpers ----------
__device__ inline unsigned short f2bf(float f) {
  union { float f; unsigned u; } v; v.f = f;
  unsigned r = v.u + 0x7fffu + ((v.u >> 16) & 1u);   // round-to-nearest-even
  return (unsigned short)(r >> 16);
}
__device__ inline float bf2f(unsigned short u) {
  union { unsigned u; float f; } v; v.u = ((unsigned)u) << 16;
  return v.f;
}
__device__ inline float2 bfp2f2(unsigned u) {       // packed bf16x2 -> float2
  union { unsigned u; float f; } a, b;
  a.u = u << 16;
  b.u = u & 0xffff0000u;
  float2 r; r.x = a.f; r.y = b.f; return r;
}
// split v into hi=bf16(v), lo=bf16(v-hi); returns packed pair for 2 values
__device__ inline void hilo2(float v0, float v1, unsigned& h, unsigned& l) {
  unsigned short h0 = f2bf(v0); float r0 = v0 - bf2f(h0);
  unsigned short h1 = f2bf(v1); float r1 = v1 - bf2f(h1);
  h = (unsigned)h0 | ((unsigned)f2bf(0.f), (unsigned)h1 << 16);
  h = (unsigned)h0 | ((unsigned)h1 << 16);
  l = (unsigned)f2bf(r0) | ((unsigned)f2bf(r1) << 16);
}

// ---------------- CSR build: bucketed two-pass sort ----------------
__global__ __launch_bounds__(256) void bucket_count_kernel(
    const int* __restrict__ src, const int* __restrict__ dst,
    int* __restrict__ bcnt, int* __restrict__ cnt_out, int E, int NB) {
  __shared__ int hist[MAXNB];
  int tid = threadIdx.x;
  for (int i = tid; i < MAXNB; i += 256) hist[i] = 0;
  __syncthreads();
  int e0 = blockIdx.x * BCH;
  #pragma unroll
  for (int k = 0; k < BCH/256; ++k) {
    int e = e0 + k*256 + tid;
    if (e < E) {
      atomicAdd(&hist[dst[e] >> 8], 1);
      atomicAdd(&cnt_out[src[e]], 1);
    }
  }
  __syncthreads();
  for (int i = tid; i < NB; i += 256)
    if (hist[i]) atomicAdd(&bcnt[i], hist[i]);
}

__global__ __launch_bounds__(256) void bucket_scan_kernel(
    const int* __restrict__ bcnt, int* __restrict__ bbase, int* __restrict__ bcur,
    int* __restrict__ rp, int NB, int N, int E) {
  __shared__ int sh[256];
  int t = threadIdx.x;
  int base = t * 4;
  int v0 = (base+0 < NB) ? bcnt[base+0] : 0;
  int v1 = (base+1 < NB) ? bcnt[base+1] : 0;
  int v2 = (base+2 < NB) ? bcnt[base+2] : 0;
  int v3 = (base+3 < NB) ? bcnt[base+3] : 0;
  int s = v0+v1+v2+v3;
  sh[t] = s;
  __syncthreads();
  for (int off=1; off<256; off<<=1){
    int x = (t >= off) ? sh[t-off] : 0;
    __syncthreads();
    sh[t] += x;
    __syncthreads();
  }
  int run = sh[t] - s;
  if (base+0 <= NB) { bbase[base+0] = run; if (base+0 < NB) bcur[base+0] = run; } run += v0;
  if (base+1 <= NB) { bbase[base+1] = run; if (base+1 < NB) bcur[base+1] = run; } run += v1;
  if (base+2 <= NB) { bbase[base+2] = run; if (base+2 < NB) bcur[base+2] = run; } run += v2;
  if (base+3 <= NB) { bbase[base+3] = run; if (base+3 < NB) bcur[base+3] = run; }
  if (t == 0) rp[N] = E;
}

__global__ __launch_bounds__(256) void bin_kernel(
    const int* __restrict__ src, const int* __restrict__ dst,
    int* __restrict__ bcur, uint2* __restrict__ ebuf, int E, int NB) {
  __shared__ int hist[MAXNB];
  __shared__ int scanb[MAXNB];
  __shared__ int rbase[MAXNB];
  __shared__ int lcur[MAXNB];
  __shared__ int tmp[256];
  __shared__ uint2 stage[BCH];
  int tid = threadIdx.x;
  int e0 = blockIdx.x * BCH;
  int nedge = E - e0; if (nedge > BCH) nedge = BCH; if (nedge < 0) nedge = 0;
  for (int i = tid; i < MAXNB; i += 256) hist[i] = 0;
  __syncthreads();
  #pragma unroll
  for (int k = 0; k < BCH/256; ++k) {
    int e = e0 + k*256 + tid;
    if (e < E) atomicAdd(&hist[dst[e] >> 8], 1);
  }
  __syncthreads();
  {
    int base = tid * 4;
    int v0 = hist[base+0], v1 = hist[base+1], v2 = hist[base+2], v3 = hist[base+3];
    int s = v0+v1+v2+v3;
    tmp[tid] = s;
    __syncthreads();
    for (int off=1; off<256; off<<=1){
      int x = (tid >= off) ? tmp[tid-off] : 0;
      __syncthreads();
      tmp[tid] += x;
      __syncthreads();
    }
    int run = tmp[tid] - s;
    scanb[base+0] = run; run += v0;
    scanb[base+1] = run; run += v1;
    scanb[base+2] = run; run += v2;
    scanb[base+3] = run;
  }
  __syncthreads();
  for (int i = tid; i < NB; i += 256) {
    int h = hist[i];
    rbase[i] = h ? atomicAdd(&bcur[i], h) : 0;
    lcur[i] = scanb[i];
  }
  __syncthreads();
  #pragma unroll
  for (int k = 0; k < BCH/256; ++k) {
    int e = e0 + k*256 + tid;
    if (e < E) {
      int d = dst[e];
      int b = d >> 8;
      int p = atomicAdd(&lcur[b], 1);
      stage[p] = make_uint2((unsigned)src[e], (unsigned)d);
    }
  }
  __syncthreads();
  for (int i = tid; i < nedge; i += 256) {
    uint2 ed = stage[i];
    int b = (int)(ed.y >> 8);
    ebuf[rbase[b] + (i - scanb[b])] = ed;
  }
}

__global__ __launch_bounds__(256) void finalize_kernel(
    const uint2* __restrict__ ebuf, const int* __restrict__ bbase,
    int* __restrict__ rp, float* __restrict__ din_is,
    int* __restrict__ col, int N) {
  __shared__ int lcnt[256];
  __shared__ int lrp[257];
  __shared__ int lcur[256];
  __shared__ int tmp[256];
  __shared__ int colbuf[BCAP];
  int b = blockIdx.x;
  int tid = threadIdx.x;
  int node0 = b << 8;
  int e0 = bbase[b], e1 = bbase[b+1];
  int ne = e1 - e0;
  lcnt[tid] = 0;
  __syncthreads();
  for (int i = tid; i < ne; i += 256)
    atomicAdd(&lcnt[ebuf[e0+i].y & 255], 1);
  __syncthreads();
  int c = lcnt[tid];
  tmp[tid] = c;
  __syncthreads();
  for (int off=1; off<256; off<<=1){
    int x = (tid >= off) ? tmp[tid-off] : 0;
    __syncthreads();
    tmp[tid] += x;
    __syncthreads();
  }
  lrp[tid] = tmp[tid] - c;
  lcur[tid] = tmp[tid] - c;
  if (tid == 255) lrp[256] = tmp[255];
  __syncthreads();
  int node = node0 + tid;
  if (node < N) {
    rp[node] = e0 + lrp[tid];
    int cc = c < 1 ? 1 : c;
    din_is[node] = rsqrtf((float)cc);
  }
  if (ne <= BCAP) {
    for (int i = tid; i < ne; i += 256) {
      uint2 ed = ebuf[e0+i];
      int p = atomicAdd(&lcur[ed.y & 255], 1);
      colbuf[p] = (int)ed.x;
    }
    __syncthreads();
    for (int i = tid; i < ne; i += 256) col[e0+i] = colbuf[i];
  } else {
    for (int i = tid; i < ne; i += 256) {
      uint2 ed = ebuf[e0+i];
      int p = atomicAdd(&lcur[ed.y & 255], 1);
      col[e0+p] = (int)ed.x;
    }
  }
}

__global__ void invsqrt_dout_kernel(const int* __restrict__ cout,
                                    float* __restrict__ dout_is, int N) {
  int i = blockIdx.x * blockDim.x + threadIdx.x;
  if (i < N) {
    int b = cout[i]; if (b < 1) b = 1;
    dout_is[i] = rsqrtf((float)b);
  }
}

// ---------------- W -> transposed bf16 hi/lo: Wt[n][k], padded to npad rows ----------------
__global__ void wt_hilo_kernel(const float* __restrict__ W, unsigned short* __restrict__ Wthi,
                               unsigned short* __restrict__ Wtlo, int nreal, int npad) {
  int idx = blockIdx.x * blockDim.x + threadIdx.x;   // over npad*128
  if (idx >= npad * 128) return;
  int n = idx >> 7;
  int k = idx & 127;
  float v = (n < nreal) ? W[k * nreal + n] : 0.f;
  unsigned short h = f2bf(v);
  float r = v - bf2f(h);
  Wthi[idx] = h;
  Wtlo[idx] = f2bf(r);
}

// ---------------- cast x (fp32 row) -> bf16 row pre-scaled by dout_is ----------------
__global__ void cast_scale_kernel(const float* __restrict__ x, const float* __restrict__ dout_is,
                                  unsigned* __restrict__ xb2, int n4) {
  int i = blockIdx.x * blockDim.x + threadIdx.x;
  if (i >= n4) return;
  float4 v = ((const float4*)x)[i];
  int row = i >> 5;
  float sc = dout_is[row];
  unsigned lo = (unsigned)f2bf(v.x * sc) | ((unsigned)f2bf(v.y * sc) << 16);
  unsigned hi = (unsigned)f2bf(v.z * sc) | ((unsigned)f2bf(v.w * sc) << 16);
  ((uint2*)xb2)[i] = make_uint2(lo, hi);
}

// ---------------- aggregation over bf16 rows, D=128, hi/lo bf16 output ----------------
__device__ inline void acc8(float* a, uint4 v) {
  float2 f;
  f = bfp2f2(v.x); a[0]+=f.x; a[1]+=f.y;
  f = bfp2f2(v.y); a[2]+=f.x; a[3]+=f.y;
  f = bfp2f2(v.z); a[4]+=f.x; a[5]+=f.y;
  f = bfp2f2(v.w); a[6]+=f.x; a[7]+=f.y;
}

__global__ __launch_bounds__(256) void agg128_bf16_kernel(
    const uint4* __restrict__ hb4,
    const int* __restrict__ rp, const int* __restrict__ col,
    const float* __restrict__ din_is,
    uint4* __restrict__ Ahi, uint4* __restrict__ Alo, int N) {
  int wave = (blockIdx.x * blockDim.x + threadIdx.x) >> 6;
  int lane = threadIdx.x & 63;
  int g = lane >> 4, j = lane & 15;
  int d = wave * 4 + g;
  if (d >= N) return;
  int s0 = rp[d], s1 = rp[d+1];
  float a[8] = {0.f,0.f,0.f,0.f,0.f,0.f,0.f,0.f};
  int e = s0;
  for (; e + 4 <= s1; e += 4) {
    int c0 = col[e], c1 = col[e+1], c2 = col[e+2], c3 = col[e+3];
    uint4 v0 = hb4[(size_t)c0*16 + j];
    uint4 v1 = hb4[(size_t)c1*16 + j];
    uint4 v2 = hb4[(size_t)c2*16 + j];
    uint4 v3 = hb4[(size_t)c3*16 + j];
    acc8(a, v0); acc8(a, v1); acc8(a, v2); acc8(a, v3);
  }
  for (; e < s1; ++e) {
    uint4 v = hb4[(size_t)col[e]*16 + j];
    acc8(a, v);
  }
  float di = din_is[d];
  uint4 H, L;
  hilo2(a[0]*di, a[1]*di, H.x, L.x);
  hilo2(a[2]*di, a[3]*di, H.y, L.y);
  hilo2(a[4]*di, a[5]*di, H.z, L.z);
  hilo2(a[6]*di, a[7]*di, H.w, L.w);
  Ahi[(size_t)d*16 + j] = H;
  Alo[(size_t)d*16 + j] = L;
}

// ---------------- MFMA GEMM: Out[N,NOUT] = (Ahi+Alo)[N,128] @ Wt^T, hi/lo 3-product ----------------
// 16x16x32 bf16 MFMA. Block = 4 waves x 16 rows = 64 rows. No LDS.
template<int NCT, bool BF16OUT>
__global__ __launch_bounds__(256) void gemm_mfma_kernel(
    const uint4* __restrict__ Ahi, const uint4* __restrict__ Alo,
    const uint4* __restrict__ Bhi, const uint4* __restrict__ Blo,  // Wt [NCT*16][128] bf16
    const float* __restrict__ bias, float* __restrict__ Out,
    unsigned short* __restrict__ OutB, const float* __restrict__ rowscale, int N) {
  int wave = threadIdx.x >> 6;
  int lane = threadIdx.x & 63;
  int quad = lane >> 4, l15 = lane & 15;
  int row0 = blockIdx.x * 64 + wave * 16;
  int row = row0 + l15;
  int rl = row < N ? row : N - 1;
  floatx4 acc[NCT];
  #pragma unroll
  for (int ct = 0; ct < NCT; ++ct) acc[ct] = (floatx4){0.f, 0.f, 0.f, 0.f};
  #pragma unroll
  for (int kc = 0; kc < 4; ++kc) {
    uint4 ah = Ahi[(size_t)rl*16 + kc*4 + quad];
    uint4 al = Alo[(size_t)rl*16 + kc*4 + quad];
    #pragma unroll
    for (int ct = 0; ct < NCT; ++ct) {
      int nr = ct*16 + l15;
      uint4 bh = Bhi[nr*16 + kc*4 + quad];
      uint4 bl = Blo[nr*16 + kc*4 + quad];
      acc[ct] = __builtin_amdgcn_mfma_f32_16x16x32_bf16(asbf(ah), asbf(bh), acc[ct], 0, 0, 0);
      acc[ct] = __builtin_amdgcn_mfma_f32_16x16x32_bf16(asbf(ah), asbf(bl), acc[ct], 0, 0, 0);
      acc[ct] = __builtin_amdgcn_mfma_f32_16x16x32_bf16(asbf(al), asbf(bh), acc[ct], 0, 0, 0);
    }
  }
  if constexpr (BF16OUT) {
    #pragma unroll
    for (int r = 0; r < 4; ++r) {
      int grow = row0 + quad*4 + r;
      if (grow < N) {
        float sc = rowscale[grow];
        #pragma unroll
        for (int ct = 0; ct < NCT; ++ct) {
          int colc = ct*16 + l15;
          if (colc < 40) OutB[(size_t)grow*40 + colc] = f2bf(acc[ct][r] * sc);
        }
      }
    }
  } else {
    #pragma unroll
    for (int ct = 0; ct < NCT; ++ct) {
      int colc = ct*16 + l15;
      float bs = bias[colc];
      #pragma unroll
      for (int r = 0; r < 4; ++r) {
        int grow = row0 + quad*4 + r;
        if (grow < N) Out[(size_t)grow*128 + colc] = acc[ct][r] + bs;
      }
    }
  }
}

// ---------------- BatchNorm ----------------
__global__ void bn_reduce_kernel(const float* __restrict__ h, float* __restrict__ gsum,
                                 float* __restrict__ gsumsq, int N, int rpb) {
  int f = threadIdx.x;
  int r0 = blockIdx.x * rpb;
  int r1 = r0 + rpb; if (r1 > N) r1 = N;
  float s = 0.f, ss = 0.f;
  for (int r = r0; r < r1; ++r) {
    float v = h[(size_t)r*128 + f];
    s += v; ss += v*v;
  }
  atomicAdd(&gsum[f], s);
  atomicAdd(&gsumsq[f], ss);
}

__global__ void bn_params_kernel(const float* __restrict__ gsum, const float* __restrict__ gsumsq,
                                 const float* __restrict__ g, const float* __restrict__ be,
                                 float* __restrict__ colA, float* __restrict__ colB, float invN) {
  int f = threadIdx.x;
  float mu  = gsum[f] * invN;
  float var = gsumsq[f] * invN - mu*mu;
  if (var < 0.f) var = 0.f;
  float rs = rsqrtf(var + 1e-5f);
  float a = g[f] * rs;
  colA[f] = a;
  colB[f] = be[f] - mu*a;
}

// bf16 out, pre-scaled by dout_is (feeds the next gather)
__global__ void bn_apply_bf16_kernel(const float* __restrict__ raw, const float* __restrict__ colA,
                                     const float* __restrict__ colB, const float* __restrict__ dout_is,
                                     unsigned* __restrict__ outb, int n4) {
  int i = blockIdx.x * blockDim.x + threadIdx.x;
  if (i >= n4) return;
  float4 v = ((const float4*)raw)[i];
  int c4 = i & 31;
  int row = i >> 5;
  float sc = dout_is[row];
  float4 a = ((const float4*)colA)[c4];
  float4 b = ((const float4*)colB)[c4];
  float x0 = fmaxf(v.x*a.x + b.x, 0.f) * sc;
  float x1 = fmaxf(v.y*a.y + b.y, 0.f) * sc;
  float x2 = fmaxf(v.z*a.z + b.z, 0.f) * sc;
  float x3 = fmaxf(v.w*a.w + b.w, 0.f) * sc;
  unsigned lo = (unsigned)f2bf(x0) | ((unsigned)f2bf(x1) << 16);
  unsigned hi = (unsigned)f2bf(x2) | ((unsigned)f2bf(x3) << 16);
  ((uint2*)outb)[i] = make_uint2(lo, hi);
}

// bf16 hi/lo out, unscaled (feeds layer-3 MFMA GEMM)
__global__ void bn_apply_hilo_kernel(const float* __restrict__ raw, const float* __restrict__ colA,
                                     const float* __restrict__ colB,
                                     uint4* __restrict__ Ahi, uint4* __restrict__ Alo, int n8) {
  int i = blockIdx.x * blockDim.x + threadIdx.x;   // one uint4 (8 cols) per thread
  if (i >= n8) return;
  int j = i & 15;                                  // slot in row
  float4 v0 = ((const float4*)raw)[2*i];
  float4 v1 = ((const float4*)raw)[2*i+1];
  float4 a0 = ((const float4*)colA)[2*j];
  float4 a1 = ((const float4*)colA)[2*j+1];
  float4 b0 = ((const float4*)colB)[2*j];
  float4 b1 = ((const float4*)colB)[2*j+1];
  float y0 = fmaxf(v0.x*a0.x + b0.x, 0.f);
  float y1 = fmaxf(v0.y*a0.y + b0.y, 0.f);
  float y2 = fmaxf(v0.z*a0.z + b0.z, 0.f);
  float y3 = fmaxf(v0.w*a0.w + b0.w, 0.f);
  float y4 = fmaxf(v1.x*a1.x + b1.x, 0.f);
  float y5 = fmaxf(v1.y*a1.y + b1.y, 0.f);
  float y6 = fmaxf(v1.z*a1.z + b1.z, 0.f);
  float y7 = fmaxf(v1.w*a1.w + b1.w, 0.f);
  uint4 H, L;
  hilo2(y0, y1, H.x, L.x);
  hilo2(y2, y3, H.y, L.y);
  hilo2(y4, y5, H.z, L.z);
  hilo2(y6, y7, H.w, L.w);
  Ahi[i] = H;
  Alo[i] = L;
}

// ---------------- layer 3: aggregate 40-dim bf16 (pre-scaled) + bias + log_softmax ----------------
__global__ __launch_bounds__(256) void final_kernel(
    const unsigned* __restrict__ tb,   // N rows x 20 dwords (40 bf16)
    const int* __restrict__ rp, const int* __restrict__ col,
    const float* __restrict__ din_is, const float* __restrict__ b3,
    float* __restrict__ out, int N) {
  int wave = (blockIdx.x * blockDim.x + threadIdx.x) >> 6;
  int g = (threadIdx.x >> 5) & 1;
  int j = threadIdx.x & 31;
  int d = wave * 2 + g;
  if (d >= N) return;
  bool act = (j < 20);
  int s0 = rp[d], s1 = rp[d+1];
  float a0 = 0.f, a1 = 0.f;
  int e = s0;
  for (; e + 4 <= s1; e += 4) {
    int c0 = col[e], c1 = col[e+1], c2 = col[e+2], c3 = col[e+3];
    unsigned u0 = act ? tb[(size_t)c0*20 + j] : 0u;
    unsigned u1 = act ? tb[(size_t)c1*20 + j] : 0u;
    unsigned u2 = act ? tb[(size_t)c2*20 + j] : 0u;
    unsigned u3 = act ? tb[(size_t)c3*20 + j] : 0u;
    float2 f0 = bfp2f2(u0), f1 = bfp2f2(u1), f2 = bfp2f2(u2), f3 = bfp2f2(u3);
    a0 += (f0.x + f1.x) + (f2.x + f3.x);
    a1 += (f0.y + f1.y) + (f2.y + f3.y);
  }
  for (; e < s1; ++e) {
    unsigned u = act ? tb[(size_t)col[e]*20 + j] : 0u;
    float2 f = bfp2f2(u);
    a0 += f.x; a1 += f.y;
  }
  float di = din_is[d];
  float z0 = act ? di*a0 + b3[2*j]   : -1e30f;
  float z1 = act ? di*a1 + b3[2*j+1] : -1e30f;
  float m = fmaxf(z0, z1);
  #pragma unroll
  for (int off=16; off>0; off>>=1) m = fmaxf(m, __shfl_xor(m, off, 32));
  float s = act ? (expf(z0-m) + expf(z1-m)) : 0.f;
  #pragma unroll
  for (int off=16; off>0; off>>=1) s += __shfl_xor(s, off, 32);
  float lg = logf(s);
  if (act) {
    float2 o = make_float2(z0 - m - lg, z1 - m - lg);
    ((float2*)(out + (size_t)d*40))[j] = o;
  }
}

// ---------------- host ----------------
extern "C" void kernel_launch(void* const* d_in, const int* in_sizes, int n_in,
                              void* d_out, int out_size, void* d_ws, size_t ws_size,
                              hipStream_t stream) {
  const float* x   = (const float*)d_in[0];
  const int*   src = (const int*)d_in[1];
  const int*   dst = (const int*)d_in[2];
  const float* W1  = (const float*)d_in[3];
  const float* b1  = (const float*)d_in[4];
  const float* g1  = (const float*)d_in[5];
  const float* be1 = (const float*)d_in[6];
  const float* W2  = (const float*)d_in[7];
  const float* b2  = (const float*)d_in[8];
  const float* g2  = (const float*)d_in[9];
  const float* be2 = (const float*)d_in[10];
  const float* W3  = (const float*)d_in[11];
  const float* b3  = (const float*)d_in[12];
  const int E = in_sizes[1];
  const int D = in_sizes[4];     // 128
  const int N = in_sizes[0] / D; // 100000
  float* out = (float*)d_out;

  char* p = (char*)d_ws;
  auto alloc = [&](size_t bytes) { char* q = p; p += (bytes + 255) & ~(size_t)255; return q; };
  int* rp        = (int*)alloc((size_t)(N+1)*4);
  int* cnt_out   = (int*)alloc((size_t)N*4);
  float* din_is  = (float*)alloc((size_t)N*4);
  float* dout_is = (float*)alloc((size_t)N*4);
  float* gsum    = (float*)alloc((size_t)D*4);
  float* gsumsq  = (float*)alloc((size_t)D*4);
  float* colAp   = (float*)alloc((size_t)D*4);
  float* colBp   = (float*)alloc((size_t)D*4);
  int* bcnt      = (int*)alloc((size_t)MAXNB*4);
  int* bbase     = (int*)alloc((size_t)(MAXNB+1)*4);
  int* bcur      = (int*)alloc((size_t)MAXNB*4);
  unsigned short* Wt1hi = (unsigned short*)alloc(128*128*2);
  unsigned short* Wt1lo = (unsigned short*)alloc(128*128*2);
  unsigned short* Wt2hi = (unsigned short*)alloc(128*128*2);
  unsigned short* Wt2lo = (unsigned short*)alloc(128*128*2);
  unsigned short* Wt3hi = (unsigned short*)alloc(48*128*2);
  unsigned short* Wt3lo = (unsigned short*)alloc(48*128*2);
  int*   col     = (int*)alloc((size_t)E*4);
  float* bufA    = (float*)alloc((size_t)N*D*4);      // fp32 GEMM output
  uint4* Ahi     = (uint4*)alloc((size_t)N*D*2);      // bf16 hi
  uint4* Alo     = (uint4*)alloc((size_t)N*D*2);      // bf16 lo
  unsigned* bf16buf = (unsigned*)alloc((size_t)N*D*2);
  // ebuf aliases bufA: CSR build finishes before bufA's first write
  uint2* ebuf = (uint2*)bufA;

  const int NB = (N + 255) >> 8;
  int nbN = (N + 255)/256;
  int ebB = (E + BCH - 1)/BCH;

  hipMemsetAsync(cnt_out, 0, (size_t)N*4, stream);
  hipMemsetAsync(bcnt, 0, (size_t)MAXNB*4, stream);
  wt_hilo_kernel<<<(128*128+255)/256, 256, 0, stream>>>(W1, Wt1hi, Wt1lo, 128, 128);
  wt_hilo_kernel<<<(128*128+255)/256, 256, 0, stream>>>(W2, Wt2hi, Wt2lo, 128, 128);
  wt_hilo_kernel<<<(48*128+255)/256, 256, 0, stream>>>(W3, Wt3hi, Wt3lo, 40, 48);
  bucket_count_kernel<<<ebB, 256, 0, stream>>>(src, dst, bcnt, cnt_out, E, NB);
  invsqrt_dout_kernel<<<nbN, 256, 0, stream>>>(cnt_out, dout_is, N);
  bucket_scan_kernel<<<1, 256, 0, stream>>>(bcnt, bbase, bcur, rp, NB, N, E);
  bin_kernel<<<ebB, 256, 0, stream>>>(src, dst, bcur, ebuf, E, NB);
  finalize_kernel<<<NB, 256, 0, stream>>>(ebuf, bbase, rp, din_is, col, N);

  int aggb   = ((N + 3)/4*64 + 255)/256;    // 4 dst per wave
  int finb   = ((N + 1)/2*64 + 255)/256;    // 2 dst per wave
  int gemb   = (N + 63)/64;                 // 64 rows per block
  int rpb  = (N + 511)/512;
  int nel4 = (N*D)/4;
  int nel8 = (N*D)/8;

  // layer 1
  cast_scale_kernel<<<(nel4+255)/256, 256, 0, stream>>>(x, dout_is, bf16buf, nel4);
  agg128_bf16_kernel<<<aggb, 256, 0, stream>>>((const uint4*)bf16buf, rp, col, din_is, Ahi, Alo, N);
  gemm_mfma_kernel<8,false><<<gemb, 256, 0, stream>>>(Ahi, Alo, (const uint4*)Wt1hi, (const uint4*)Wt1lo,
                                                      b1, bufA, nullptr, nullptr, N);
  hipMemsetAsync(gsum, 0, (size_t)D*4, stream);
  hipMemsetAsync(gsumsq, 0, (size_t)D*4, stream);
  bn_reduce_kernel<<<512, 128, 0, stream>>>(bufA, gsum, gsumsq, N, rpb);
  bn_params_kernel<<<1, 128, 0, stream>>>(gsum, gsumsq, g1, be1, colAp, colBp, 1.0f/(float)N);
  bn_apply_bf16_kernel<<<(nel4+255)/256, 256, 0, stream>>>(bufA, colAp, colBp, dout_is, bf16buf, nel4);

  // layer 2
  agg128_bf16_kernel<<<aggb, 256, 0, stream>>>((const uint4*)bf16buf, rp, col, din_is, Ahi, Alo, N);
  gemm_mfma_kernel<8,false><<<gemb, 256, 0, stream>>>(Ahi, Alo, (const uint4*)Wt2hi, (const uint4*)Wt2lo,
                                                      b2, bufA, nullptr, nullptr, N);
  hipMemsetAsync(gsum, 0, (size_t)D*4, stream);
  hipMemsetAsync(gsumsq, 0, (size_t)D*4, stream);
  bn_reduce_kernel<<<512, 128, 0, stream>>>(bufA, gsum, gsumsq, N, rpb);
  bn_params_kernel<<<1, 128, 0, stream>>>(gsum, gsumsq, g2, be2, colAp, colBp, 1.0f/(float)N);
  bn_apply_hilo_kernel<<<(nel8+255)/256, 256, 0, stream>>>(bufA, colAp, colBp, Ahi, Alo, nel8);

  // layer 3: MFMA GEMM to 40 dims (bf16 out pre-scaled by dout), then agg + softmax
  gemm_mfma_kernel<3,true><<<gemb, 256, 0, stream>>>(Ahi, Alo, (const uint4*)Wt3hi, (const uint4*)Wt3lo,
                                                     nullptr, nullptr, (unsigned short*)bf16buf, dout_is, N);
  final_kernel<<<finb, 256, 0, stream>>>((const unsigned*)bf16buf, rp, col, din_is, b3, out, N);
}